// Round 9
// baseline (1040.270 us; speedup 1.0000x reference)
//
#include <hip/hip_runtime.h>
#include <hip/hip_bf16.h>

typedef unsigned short u16;
typedef __attribute__((ext_vector_type(8))) short bf16x8_t;
typedef __attribute__((ext_vector_type(4))) float f32x4_t;

#define DEV __device__ __forceinline__

constexpr int cB = 2, cT = 2048, cD = 2048;
constexpr int cN = 8, cK = 2, cH = 256, cF = 8192;
constexpr int cBT = cB * cT;
constexpr float cEPS = 1e-6f;
constexpr float cQS = 0.0625f;     // 256^-0.5
constexpr float cCAP = 50.0f;
constexpr int cWIN = 512;
constexpr int cNH = 12;            // fused qkv heads per token: 8 q + 2 k + 2 v

DEV u16 f2bf(float f) {
  union { float f; unsigned u; } c; c.f = f;
  unsigned u = c.u;
  return (u16)((u + 0x7fffu + ((u >> 16) & 1u)) >> 16);   // RNE
}
DEV float bf2f(u16 h) {
  union { unsigned u; float f; } c; c.u = ((unsigned)h) << 16;
  return c.f;
}
DEV float g4(const float4& v, int k) { return k == 0 ? v.x : k == 1 ? v.y : k == 2 ? v.z : v.w; }
DEV void store_bf4(u16* p, float a, float b, float c, float d) {
  union { u16 h[4]; uint2 v; } o;
  o.h[0] = f2bf(a); o.h[1] = f2bf(b); o.h[2] = f2bf(c); o.h[3] = f2bf(d);
  *(uint2*)p = o.v;
}
// tanh via hardware exp+rcp: tanh(x) = 1 - 2/(e^{2x}+1). rel err ~1e-5.
DEV float tanh_fast(float x) {
  float e2 = __expf(2.0f * x);
  return 1.0f - 2.0f * __builtin_amdgcn_rcpf(e2 + 1.0f);
}
// gelu-tanh: 0.5x(1+tanh(u)) = x * (1 - 1/(e^{2u}+1))
DEV float gelu_fast(float x) {
  float u = 1.5957691216057308f * (x + 0.044715f * x * x * x);  // 2*0.7978845608
  float e2 = __expf(u);
  return x * (1.0f - __builtin_amdgcn_rcpf(e2 + 1.0f));
}

// block=256 sum reduction (4 waves)
DEV float block_sum256(float v, float* sbuf) {
  #pragma unroll
  for (int m = 32; m > 0; m >>= 1) v += __shfl_xor(v, m, 64);
  int wid = threadIdx.x >> 6;
  if ((threadIdx.x & 63) == 0) sbuf[wid] = v;
  __syncthreads();
  float tot = sbuf[0] + sbuf[1] + sbuf[2] + sbuf[3];
  __syncthreads();
  return tot;
}
// 4 values reduced with a single syncthreads round
DEV void block_sum256x4(float v[4], float* sbuf /*>=16*/) {
  #pragma unroll
  for (int m = 32; m > 0; m >>= 1) {
    #pragma unroll
    for (int k = 0; k < 4; k++) v[k] += __shfl_xor(v[k], m, 64);
  }
  int wid = threadIdx.x >> 6;
  if ((threadIdx.x & 63) == 0) *(float4*)(sbuf + wid * 4) = make_float4(v[0], v[1], v[2], v[3]);
  __syncthreads();
  #pragma unroll
  for (int k = 0; k < 4; k++) v[k] = sbuf[k] + sbuf[4 + k] + sbuf[8 + k] + sbuf[12 + k];
  __syncthreads();
}

#define GLD_LDS16(gp, lp) __builtin_amdgcn_global_load_lds( \
    (const __attribute__((address_space(1))) void*)(gp),    \
    (__attribute__((address_space(3))) void*)(lp), 16, 0, 0)

#define WAITV(n) asm volatile("s_waitcnt vmcnt(" #n ")" ::: "memory")

// ===================== weight transpose + f32->bf16 cast =====================
__global__ __launch_bounds__(256) void k_transpose_cast(
    const float* __restrict__ src, u16* __restrict__ dst, int R, int C, int gu) {
  __shared__ float tile[32][33];
  size_t base = (size_t)blockIdx.z * R * C;
  int c0 = blockIdx.x * 32, r0 = blockIdx.y * 32;
  int tx = threadIdx.x & 31, ty = threadIdx.x >> 5;
  #pragma unroll
  for (int i = 0; i < 4; i++)
    tile[ty + i * 8][tx] = src[base + (size_t)(r0 + ty + i * 8) * C + c0 + tx];
  __syncthreads();
  #pragma unroll
  for (int i = 0; i < 4; i++) {
    int c = c0 + ty + i * 8;
    int n = (gu < 0) ? c : (((c >> 4) << 5) + (gu << 4) + (c & 15));
    dst[base + (size_t)n * R + r0 + tx] = f2bf(tile[tx][ty + i * 8]);
  }
}

// ===================== RoPE sin/cos table: [BT][128] float2 =====================
__global__ __launch_bounds__(256) void k_rope_table(
    const int* __restrict__ pos, float2* __restrict__ rt) {
  int idx = blockIdx.x * 256 + threadIdx.x;    // over BT*128
  int bt = idx >> 7, j = idx & 127;
  float p = (float)pos[bt];
  float ts = powf(10000.0f, (2.0f * j) * (1.0f / cH));
  float si = p / ts;
  rt[idx] = make_float2(sinf(si), cosf(si));
}

// ===================== AltUp predict + pre-attn RMSNorm (float4) =====================
__global__ __launch_bounds__(256) void k_predict(
    const float* __restrict__ x, const float* __restrict__ router_w,
    const float* __restrict__ pred_coefs, const float* __restrict__ pre_attn_scale,
    float* __restrict__ out, u16* __restrict__ attn_in) {
  __shared__ float sbuf[16];
  int bt = blockIdx.x, tid = threadIdx.x;
  const size_t PL = (size_t)cBT * cD;
  const size_t rowb = (size_t)bt * cD;
  float4 xv[4][2];
  #pragma unroll
  for (int j = 0; j < 4; j++)
    #pragma unroll
    for (int u = 0; u < 2; u++)
      xv[j][u] = *(const float4*)(x + j * PL + rowb + (u * 256 + tid) * 4);
  float rp[4] = {0, 0, 0, 0};
  #pragma unroll
  for (int u = 0; u < 2; u++)
    #pragma unroll
    for (int k = 0; k < 4; k++) {
      int e = (u * 256 + tid) * 4 + k;
      float4 rw = *(const float4*)(router_w + (size_t)e * 4);
      float xe = g4(xv[0][u], k);
      rp[0] += xe * rw.x; rp[1] += xe * rw.y; rp[2] += xe * rw.z; rp[3] += xe * rw.w;
    }
  block_sum256x4(rp, sbuf);
  float mods[4];
  #pragma unroll
  for (int p = 0; p < 4; p++) mods[p] = tanh_fast(rp[p] * (1.0f / cD));
  float coef[4][4];
  #pragma unroll
  for (int i = 0; i < 4; i++)
    #pragma unroll
    for (int j = 0; j < 4; j++) {
      float s = 0;
      #pragma unroll
      for (int p = 0; p < 4; p++) s += mods[p] * pred_coefs[(p * 4 + i) * 4 + j];
      coef[i][j] = s;
    }
  float4 p04[2]; float ssq = 0;
  #pragma unroll
  for (int u = 0; u < 2; u++)
    #pragma unroll
    for (int i = 0; i < 4; i++) {
      float4 s = xv[i][u];
      #pragma unroll
      for (int j = 0; j < 4; j++) {
        s.x += coef[i][j] * xv[j][u].x; s.y += coef[i][j] * xv[j][u].y;
        s.z += coef[i][j] * xv[j][u].z; s.w += coef[i][j] * xv[j][u].w;
      }
      *(float4*)(out + i * PL + rowb + (u * 256 + tid) * 4) = s;
      if (i == 0) { p04[u] = s; ssq += s.x * s.x + s.y * s.y + s.z * s.z + s.w * s.w; }
    }
  float rs = rsqrtf(block_sum256(ssq, sbuf) * (1.0f / cD) + cEPS);
  #pragma unroll
  for (int u = 0; u < 2; u++) {
    int e0 = (u * 256 + tid) * 4;
    float4 sc = *(const float4*)(pre_attn_scale + e0);
    store_bf4(attn_in + rowb + e0,
              p04[u].x * rs * (1.0f + sc.x), p04[u].y * rs * (1.0f + sc.y),
              p04[u].z * rs * (1.0f + sc.z), p04[u].w * rs * (1.0f + sc.w));
  }
}

// ============ bf16 TN GEMM: 8-wave, BK=64, 8-phase (R7-verified skeleton) ============
// R9 change: all 4 stage units of tile t+1 issue in phases 0-1 (was spread 0-3).
// ph1 WAITV(8|6) retires A1B1(t) (issued t-1.ph1 -> 5-phase coverage, was 3);
// ph3 WAITV(4|3) retires A0B0(t+1). Slot-safety identical to R7: writes to slot
// (t+1)&1 issue only after the barrier closing all reads of tile t-1.
// OUT_MODE: 0 = f32, 1 = bf16, 2 = gelu(gate)*up, 16-col interleaved N (out Nn/2 cols)
template <int MI, int OUT_MODE>
__global__ __launch_bounds__(512, 2) void k_gemm8(
    const u16* __restrict__ A, const u16* __restrict__ Bt, void* __restrict__ Cv,
    int Nn, int Kk) {
  static_assert(MI == 4 || MI == 8, "");
  constexpr int BM = MI * 32;
  constexpr int A_KS = BM * 32;            // elems per A k-subtile
  constexpr int B_KS = 256 * 32;           // elems per B k-subtile
  constexpr int BUF_E = 2 * A_KS + 2 * B_KS;
  extern __shared__ u16 lds[];             // 2 * BUF_E elems

  const int tid = threadIdx.x;
  const int wid = tid >> 6, lane = tid & 63;
  const int wr = wid >> 2, wc = wid & 3;
  const int fr = lane & 15, fq = lane >> 4;

  const int nwg = gridDim.x * gridDim.y;
  const int flat = blockIdx.y * gridDim.x + blockIdx.x;
  const int swz = (flat & 7) * (nwg >> 3) + (flat >> 3);
  const int m0 = (swz % gridDim.x) * BM;
  const int n0 = (swz / gridDim.x) * 256;
  const int NT = Kk >> 6;

  const int srow = lane >> 2, sslot = lane & 3;

  auto stageA = [&](int t, int ks) {
    u16* buf = lds + (t & 1) * BUF_E + ks * A_KS;
    #pragma unroll
    for (int i = 0; i < BM / 128; i++) {
      int row0 = i * 128 + wid * 16;
      int row = row0 + srow;
      int col = (sslot ^ ((row >> 1) & 3)) * 8;     // inverse swizzle on source
      GLD_LDS16(A + (size_t)(m0 + row) * Kk + t * 64 + ks * 32 + col, buf + row0 * 32);
    }
  };
  auto stageB = [&](int t, int ks) {
    u16* buf = lds + (t & 1) * BUF_E + 2 * A_KS + ks * B_KS;
    #pragma unroll
    for (int i = 0; i < 2; i++) {
      int row0 = i * 128 + wid * 16;
      int row = row0 + srow;
      int col = (sslot ^ ((row >> 1) & 3)) * 8;
      GLD_LDS16(Bt + (size_t)(n0 + row) * Kk + t * 64 + ks * 32 + col, buf + row0 * 32);
    }
  };
  auto readA = [&](const u16* buf, int ks, int i) -> bf16x8_t {
    int row = wr * (MI * 16) + i * 16 + fr;
    return *(const bf16x8_t*)(buf + ks * A_KS + row * 32 + (fq ^ ((row >> 1) & 3)) * 8);
  };
  auto readB = [&](const u16* buf, int ks, int j) -> bf16x8_t {
    int row = wc * 64 + j * 16 + fr;
    return *(const bf16x8_t*)(buf + 2 * A_KS + ks * B_KS + row * 32 + (fq ^ ((row >> 1) & 3)) * 8);
  };

  f32x4_t acc[MI][4];
  #pragma unroll
  for (int i = 0; i < MI; i++)
    #pragma unroll
    for (int j = 0; j < 4; j++) acc[i][j] = (f32x4_t){0.f, 0.f, 0.f, 0.f};

  // prologue: stage tile 0 fully; retire A0B0(0), leave A1B1(0) in flight
  stageA(0, 0); stageB(0, 0); stageA(0, 1); stageB(0, 1);
  if constexpr (MI == 8) WAITV(4); else WAITV(3);
  __builtin_amdgcn_s_barrier();

#define PHASE_MFMA(J0)                                                              \
  __builtin_amdgcn_s_setprio(1);                                                    \
  _Pragma("unroll")                                                                 \
  for (int i = 0; i < MI; i++) {                                                    \
    acc[i][J0]     = __builtin_amdgcn_mfma_f32_16x16x32_bf16(a0[i], b0[0], acc[i][J0], 0, 0, 0);     \
    acc[i][J0 + 1] = __builtin_amdgcn_mfma_f32_16x16x32_bf16(a0[i], b0[1], acc[i][J0 + 1], 0, 0, 0); \
  }                                                                                 \
  __builtin_amdgcn_s_setprio(0);

  for (int t = 0; t < NT; t++) {
    const u16* buf = lds + (t & 1) * BUF_E;
    const bool pf = (t + 1 < NT);
    bf16x8_t a0[MI], b0[2];

    // ---- phase 0: ks=0, n-frags 0,1 ; stage A0B0(t+1)
    #pragma unroll
    for (int i = 0; i < MI; i++) a0[i] = readA(buf, 0, i);
    b0[0] = readB(buf, 0, 0); b0[1] = readB(buf, 0, 1);
    if (pf) { stageA(t + 1, 0); stageB(t + 1, 0); }
    asm volatile("" ::: "memory");   // pin: ph0 stage-pair older than ph1's
    __builtin_amdgcn_s_barrier();
    PHASE_MFMA(0)
    __builtin_amdgcn_s_barrier();

    // ---- phase 1: ks=0, n-frags 2,3 ; stage A1B1(t+1); wait retires A1B1(t)
    b0[0] = readB(buf, 0, 2); b0[1] = readB(buf, 0, 3);
    if (pf) { stageA(t + 1, 1); stageB(t + 1, 1); }
    if (pf) { if constexpr (MI == 8) WAITV(8); else WAITV(6); } else WAITV(0);
    __builtin_amdgcn_s_barrier();
    PHASE_MFMA(2)
    __builtin_amdgcn_s_barrier();

    // ---- phase 2: ks=1, n-frags 0,1
    #pragma unroll
    for (int i = 0; i < MI; i++) a0[i] = readA(buf, 1, i);
    b0[0] = readB(buf, 1, 0); b0[1] = readB(buf, 1, 1);
    __builtin_amdgcn_s_barrier();
    PHASE_MFMA(0)
    __builtin_amdgcn_s_barrier();

    // ---- phase 3: ks=1, n-frags 2,3 ; wait retires A0B0(t+1) (needed next ph0)
    b0[0] = readB(buf, 1, 2); b0[1] = readB(buf, 1, 3);
    if (pf) { if constexpr (MI == 8) WAITV(4); else WAITV(3); }
    __builtin_amdgcn_s_barrier();
    PHASE_MFMA(2)
    __builtin_amdgcn_s_barrier();
  }
#undef PHASE_MFMA

  if constexpr (OUT_MODE == 2) {
    // n-frag pairs (2jp, 2jp+1) hold gate/up for the same 16 output columns
    const int Nh = Nn >> 1;
    #pragma unroll
    for (int i = 0; i < MI; i++)
      #pragma unroll
      for (int jp = 0; jp < 2; jp++) {
        int c = (n0 + wc * 64 + jp * 32) / 2 + fr;
        #pragma unroll
        for (int r = 0; r < 4; r++) {
          int m = m0 + wr * (MI * 16) + i * 16 + fq * 4 + r;
          float g = acc[i][2 * jp][r], uu = acc[i][2 * jp + 1][r];
          ((u16*)Cv)[(size_t)m * Nh + c] = f2bf(gelu_fast(g) * uu);
        }
      }
  } else {
    #pragma unroll
    for (int i = 0; i < MI; i++)
      #pragma unroll
      for (int j = 0; j < 4; j++)
        #pragma unroll
        for (int r = 0; r < 4; r++) {
          int m = m0 + wr * (MI * 16) + i * 16 + fq * 4 + r;
          int n = n0 + wc * 64 + j * 16 + fr;
          float v = acc[i][j][r];
          if (OUT_MODE == 1) ((u16*)Cv)[(size_t)m * Nn + n] = f2bf(v);
          else ((float*)Cv)[(size_t)m * Nn + n] = v;
        }
  }
}

// ===== fused QKV post: q/k RMSNorm+RoPE (table), v RMSNorm+transpose — one kernel =====
__global__ __launch_bounds__(64) void k_qkvpost(
    u16* __restrict__ qkv, const float* __restrict__ qscale,
    const float* __restrict__ kscale, const float2* __restrict__ rt,
    u16* __restrict__ vT) {
  int h = blockIdx.x % cNH, bt = blockIdx.x / cNH;
  int lane = threadIdx.x;
  u16* row = qkv + ((size_t)bt * cNH + h) * cH;
  float v[4], ssq = 0;
  #pragma unroll
  for (int m = 0; m < 4; m++) { v[m] = bf2f(row[lane + 64 * m]); ssq += v[m] * v[m]; }
  #pragma unroll
  for (int mm = 32; mm > 0; mm >>= 1) ssq += __shfl_xor(ssq, mm, 64);
  float rs = rsqrtf(ssq * (1.0f / cH) + cEPS);
  if (h < 10) {
    const float* sc = (h < 8) ? qscale : kscale;
    float os = (h < 8) ? cQS : 1.0f;
    #pragma unroll
    for (int m = 0; m < 4; m++) {
      int e = lane + 64 * m;
      v[m] = v[m] * rs * (1.0f + sc[e]);
    }
    #pragma unroll
    for (int m = 0; m < 2; m++) {
      int j = lane + 64 * m;
      float2 t = rt[bt * 128 + j];          // (sin, cos)
      float x1 = v[m], x2 = v[m + 2];
      row[j]       = f2bf((x1 * t.y - x2 * t.x) * os);
      row[j + 128] = f2bf((x2 * t.y + x1 * t.x) * os);
    }
  } else {
    int kk = h - 10;
    int b = bt / cT, t = bt % cT;
    #pragma unroll
    for (int m = 0; m < 4; m++) {
      int e = lane + 64 * m;
      vT[((size_t)(b * cK + kk) * cH + e) * cT + t] = f2bf(v[m] * rs);
    }
  }
}

// ===================== sliding-window GQA attention, 1 wave / 16-row Q tile =====================
__global__ __launch_bounds__(64) void k_attn(
    const u16* __restrict__ qkv, const u16* __restrict__ vT, u16* __restrict__ enc) {
  int t0 = blockIdx.x * 16;
  int n = blockIdx.y, b = blockIdx.z;
  int kn = n >> 2;                           // GQA group of 4
  int lane = threadIdx.x;
  int fr = lane & 15, fq = lane >> 4;
  __shared__ float P[16][33];                // +1 pad: kills 32-way conflict on transpose read

  bf16x8_t qf[8];
  const u16* qrow = qkv + ((size_t)(b * cT + t0 + fr) * cNH + n) * cH;
  #pragma unroll
  for (int ks = 0; ks < 8; ks++) qf[ks] = *(const bf16x8_t*)(qrow + ks * 32 + fq * 8);

  f32x4_t acc[16];
  #pragma unroll
  for (int ht = 0; ht < 16; ht++) acc[ht] = (f32x4_t){0.f, 0.f, 0.f, 0.f};
  float psum[4] = {0.f, 0.f, 0.f, 0.f};

  int s_lo = t0 - (cWIN - 1); if (s_lo < 0) s_lo = 0; s_lo &= ~31;
  for (int s0 = s_lo; s0 <= t0 + 15; s0 += 32) {
    f32x4_t S[2];
    S[0] = (f32x4_t){0.f, 0.f, 0.f, 0.f};
    S[1] = (f32x4_t){0.f, 0.f, 0.f, 0.f};
    #pragma unroll
    for (int c = 0; c < 2; c++) {
      const u16* krow = qkv + ((size_t)(b * cT + s0 + c * 16 + fr) * cNH + 8 + kn) * cH;
      #pragma unroll
      for (int ks = 0; ks < 8; ks++) {
        bf16x8_t kf = *(const bf16x8_t*)(krow + ks * 32 + fq * 8);
        S[c] = __builtin_amdgcn_mfma_f32_16x16x32_bf16(qf[ks], kf, S[c], 0, 0, 0);
      }
    }
    // soft-cap (fast tanh), mask, exp (fixed-max softmax: cap bounds logits to [-50,50])
    #pragma unroll
    for (int c = 0; c < 2; c++) {
      int s = s0 + c * 16 + fr;
      #pragma unroll
      for (int r = 0; r < 4; r++) {
        int t = t0 + fq * 4 + r;
        float l = cCAP * tanh_fast(S[c][r] * (1.0f / cCAP));
        float pe = (s <= t && s >= t - (cWIN - 1)) ? __expf(l) : 0.0f;
        psum[r] += pe;
        P[fq * 4 + r][c * 16 + fr] = pe;
      }
    }
    // transpose P via LDS into A-fragment layout (single wave: ds ops in order)
    bf16x8_t pf;
    #pragma unroll
    for (int e = 0; e < 8; e++) pf[e] = (short)f2bf(P[fr][fq * 8 + e]);
    #pragma unroll
    for (int ht = 0; ht < 16; ht++) {
      bf16x8_t vf = *(const bf16x8_t*)(vT + (((size_t)(b * cK + kn)) * cH + ht * 16 + fr) * cT + s0 + fq * 8);
      acc[ht] = __builtin_amdgcn_mfma_f32_16x16x32_bf16(pf, vf, acc[ht], 0, 0, 0);
    }
  }
  #pragma unroll
  for (int r = 0; r < 4; r++) {
    #pragma unroll
    for (int m = 1; m < 16; m <<= 1) psum[r] += __shfl_xor(psum[r], m, 64);
  }
  float inv[4];
  #pragma unroll
  for (int r = 0; r < 4; r++) inv[r] = 1.0f / psum[r];
  #pragma unroll
  for (int ht = 0; ht < 16; ht++)
    #pragma unroll
    for (int r = 0; r < 4; r++)
      enc[(((size_t)(b * cT + t0 + fq * 4 + r)) * cN + n) * cH + ht * 16 + fr] =
          f2bf(acc[ht][r] * inv[r]);
}

// ===================== post-attn: norm + residual + pre-FFW norm (float4) =====================
__global__ __launch_bounds__(256) void k_postattn(
    const float* __restrict__ attn_raw, const float* __restrict__ out0,
    const float* __restrict__ post_attn_scale, const float* __restrict__ pre_ffw_scale,
    float* __restrict__ ag, u16* __restrict__ h) {
  __shared__ float sbuf[4];
  int bt = blockIdx.x, tid = threadIdx.x;
  const size_t rowb = (size_t)bt * cD;
  float4 ar[2]; float ssq = 0;
  #pragma unroll
  for (int u = 0; u < 2; u++) {
    ar[u] = *(const float4*)(attn_raw + rowb + (u * 256 + tid) * 4);
    ssq += ar[u].x * ar[u].x + ar[u].y * ar[u].y + ar[u].z * ar[u].z + ar[u].w * ar[u].w;
  }
  float rs = rsqrtf(block_sum256(ssq, sbuf) * (1.0f / cD) + cEPS);
  float4 agv[2]; float ssq2 = 0;
  #pragma unroll
  for (int u = 0; u < 2; u++) {
    int e0 = (u * 256 + tid) * 4;
    float4 o0 = *(const float4*)(out0 + rowb + e0);
    float4 sc = *(const float4*)(post_attn_scale + e0);
    float4 a;
    a.x = o0.x + ar[u].x * rs * (1.0f + sc.x);
    a.y = o0.y + ar[u].y * rs * (1.0f + sc.y);
    a.z = o0.z + ar[u].z * rs * (1.0f + sc.z);
    a.w = o0.w + ar[u].w * rs * (1.0f + sc.w);
    agv[u] = a;
    *(float4*)(ag + rowb + e0) = a;
    ssq2 += a.x * a.x + a.y * a.y + a.z * a.z + a.w * a.w;
  }
  float rs2 = rsqrtf(block_sum256(ssq2, sbuf) * (1.0f / cD) + cEPS);
  #pragma unroll
  for (int u = 0; u < 2; u++) {
    int e0 = (u * 256 + tid) * 4;
    float4 sc = *(const float4*)(pre_ffw_scale + e0);
    store_bf4(h + rowb + e0,
              agv[u].x * rs2 * (1.0f + sc.x), agv[u].y * rs2 * (1.0f + sc.y),
              agv[u].z * rs2 * (1.0f + sc.z), agv[u].w * rs2 * (1.0f + sc.w));
  }
}

// ======= post-FFW norm + residual + AltUp correct, in-place on out (float4) =======
__global__ __launch_bounds__(256) void k_final(
    const float* __restrict__ ffw_raw, const float* __restrict__ ag,
    const float* __restrict__ post_ffw_scale, const float* __restrict__ cos_scale,
    const float* __restrict__ router_w, const float* __restrict__ corr_coefs,
    float* __restrict__ out) {
  __shared__ float sbuf[16];
  int bt = blockIdx.x, tid = threadIdx.x;
  const size_t PL = (size_t)cBT * cD;
  const size_t rowb = (size_t)bt * cD;
  float4 fv[2]; float ssq = 0;
  #pragma unroll
  for (int u = 0; u < 2; u++) {
    fv[u] = *(const float4*)(ffw_raw + rowb + (u * 256 + tid) * 4);
    ssq += fv[u].x * fv[u].x + fv[u].y * fv[u].y + fv[u].z * fv[u].z + fv[u].w * fv[u].w;
  }
  float rs = rsqrtf(block_sum256(ssq, sbuf) * (1.0f / cD) + cEPS);
  float4 av[2];
  float rp[4] = {0, 0, 0, 0};
  #pragma unroll
  for (int u = 0; u < 2; u++) {
    int e0 = (u * 256 + tid) * 4;
    float4 agx = *(const float4*)(ag + rowb + e0);
    float4 ps = *(const float4*)(post_ffw_scale + e0);
    float4 cs = *(const float4*)(cos_scale + e0);
    float4 a;
    a.x = (agx.x + fv[u].x * rs * (1.0f + ps.x)) * cs.x;
    a.y = (agx.y + fv[u].y * rs * (1.0f + ps.y)) * cs.y;
    a.z = (agx.z + fv[u].z * rs * (1.0f + ps.z)) * cs.z;
    a.w = (agx.w + fv[u].w * rs * (1.0f + ps.w)) * cs.w;
    av[u] = a;
    #pragma unroll
    for (int k = 0; k < 4; k++) {
      float4 rw = *(const float4*)(router_w + (size_t)(e0 + k) * 4);
      float xe = g4(a, k);
      rp[0] += xe * rw.x; rp[1] += xe * rw.y; rp[2] += xe * rw.z; rp[3] += xe * rw.w;
    }
  }
  block_sum256x4(rp, sbuf);
  float cc[4];
  #pragma unroll
  for (int i = 0; i < 4; i++) {
    float s = 1.0f;
    #pragma unroll
    for (int p = 0; p < 4; p++) s += tanh_fast(rp[p] * (1.0f / cD)) * corr_coefs[p * 4 + i];
    cc[i] = s;
  }
  #pragma unroll
  for (int u = 0; u < 2; u++) {
    size_t o = rowb + (u * 256 + tid) * 4;
    float4 p0 = *(const float4*)(out + o);
    float4 in4;
    in4.x = av[u].x - p0.x; in4.y = av[u].y - p0.y;
    in4.z = av[u].z - p0.z; in4.w = av[u].w - p0.w;
    float4 w0;
    w0.x = p0.x + cc[0] * in4.x; w0.y = p0.y + cc[0] * in4.y;
    w0.z = p0.z + cc[0] * in4.z; w0.w = p0.w + cc[0] * in4.w;
    *(float4*)(out + o) = w0;
    #pragma unroll
    for (int i = 1; i < 4; i++) {
      float4 q = *(const float4*)(out + i * PL + o);
      q.x += cc[i] * in4.x; q.y += cc[i] * in4.y;
      q.z += cc[i] * in4.z; q.w += cc[i] * in4.w;
      *(float4*)(out + i * PL + o) = q;
    }
  }
}

// =============================================================================
extern "C" void kernel_launch(void* const* d_in, const int* in_sizes, int n_in,
                              void* d_out, int out_size, void* d_ws, size_t ws_size,
                              hipStream_t stream) {
  const float* x              = (const float*)d_in[0];
  const int*   pos            = (const int*)d_in[1];
  // d_in[2] attn_mask: equals causal(pos) — recomputed from positions in-kernel
  const float* router_w       = (const float*)d_in[3];
  const float* pred_coefs     = (const float*)d_in[4];
  const float* corr_coefs     = (const float*)d_in[5];
  const float* cos_scale      = (const float*)d_in[6];
  const float* pre_attn_scale = (const float*)d_in[7];
  const float* q_w            = (const float*)d_in[8];
  const float* kv_w           = (const float*)d_in[9];
  const float* qk_q_scale     = (const float*)d_in[10];
  const float* qk_k_scale     = (const float*)d_in[11];
  const float* o_w            = (const float*)d_in[12];
  const float* post_attn_scale= (const float*)d_in[13];
  const float* pre_ffw_scale  = (const float*)d_in[14];
  const float* gate_w         = (const float*)d_in[15];
  const float* up_w           = (const float*)d_in[16];
  const float* down_w         = (const float*)d_in[17];
  const float* post_ffw_scale = (const float*)d_in[18];
  float* out = (float*)d_out;

  char* wsp = (char*)d_ws;
  size_t off = 0;
  auto take = [&](size_t nbytes) -> char* {
    char* p = wsp + off;
    off += (nbytes + 255) & ~((size_t)255);
    return p;
  };
  u16* gu_wT    = (u16*)take((size_t)2 * cF * cD * 2);          // [16384][2048], 16-col interleave
  u16* down_wT  = (u16*)take((size_t)cD * cF * 2);              // [2048][8192]
  u16* qkv_wT   = (u16*)take((size_t)cNH * cH * cD * 2);        // [3072][2048]
  u16* o_wT     = (u16*)take((size_t)cD * cN * cH * 2);         // [2048][2048]
  u16* attn_in  = (u16*)take((size_t)cBT * cD * 2);
  u16* qkvbuf   = (u16*)take((size_t)cBT * cNH * cH * 2);       // [BT][3072]
  u16* vTbuf    = (u16*)take((size_t)cB * cK * cH * cT * 2);
  u16* encbuf   = (u16*)take((size_t)cBT * cN * cH * 2);
  float* attn_raw = (float*)take((size_t)cBT * cD * 4);
  float* agbuf    = (float*)take((size_t)cBT * cD * 4);
  u16* hbuf     = (u16*)take((size_t)cBT * cD * 2);
  u16* Gcbuf    = (u16*)take((size_t)cBT * cF * 2);             // gelu(G)*U, [BT][8192]
  float* ffw_raw = (float*)take((size_t)cBT * cD * 4);
  float2* ropetab = (float2*)take((size_t)cBT * 128 * 8);
  (void)in_sizes; (void)n_in; (void)out_size; (void)ws_size;

  dim3 blk256(256), blk64(64), blk512(512);
  constexpr unsigned LDS8 = 2 * (2 * 256 * 32 + 2 * 256 * 32) * 2;   // 128 KiB
  constexpr unsigned LDS4 = 2 * (2 * 128 * 32 + 2 * 256 * 32) * 2;   //  96 KiB

  // ---- weight prep: transpose + cast to bf16 (TN layout); gate/up 16-col interleaved ----
  k_transpose_cast<<<dim3(cF / 32, cD / 32, 1), blk256, 0, stream>>>(gate_w, gu_wT, cD, cF, 0);
  k_transpose_cast<<<dim3(cF / 32, cD / 32, 1), blk256, 0, stream>>>(up_w, gu_wT, cD, cF, 1);
  k_transpose_cast<<<dim3(cD / 32, cF / 32, 1), blk256, 0, stream>>>(down_w, down_wT, cF, cD, -1);
  k_transpose_cast<<<dim3(cH / 32, cD / 32, cN), blk256, 0, stream>>>(q_w, qkv_wT, cD, cH, -1);
  k_transpose_cast<<<dim3(cH / 32, cD / 32, 2 * cK), blk256, 0, stream>>>(
      kv_w, qkv_wT + (size_t)cN * cH * cD, cD, cH, -1);
  k_transpose_cast<<<dim3(cD / 32, (cN * cH) / 32, 1), blk256, 0, stream>>>(o_w, o_wT, cN * cH, cD, -1);
  k_rope_table<<<dim3(cBT * 128 / 256), blk256, 0, stream>>>(pos, ropetab);

  // ---- AltUp predict (writes predictions into d_out) + pre-attn RMSNorm ----
  k_predict<<<dim3(cBT), blk256, 0, stream>>>(x, router_w, pred_coefs, pre_attn_scale, out, attn_in);

  // ---- fused QKV projection: [4096,2048] x [3072,2048]^T ----
  k_gemm8<4, 1><<<dim3(cBT / 128, (cNH * cH) / 256), blk512, LDS4, stream>>>(
      attn_in, qkv_wT, qkvbuf, cNH * cH, cD);

  // ---- fused QK-norm+RoPE / V-norm+transpose ----
  k_qkvpost<<<dim3(cBT * cNH), blk64, 0, stream>>>(qkvbuf, qk_q_scale, qk_k_scale, ropetab, vTbuf);

  // ---- sliding-window attention ----
  k_attn<<<dim3(cT / 16, cN, cB), blk64, 0, stream>>>(qkvbuf, vTbuf, encbuf);

  // ---- O projection + post-attn norm/residual + pre-FFW norm ----
  k_gemm8<4, 0><<<dim3(cBT / 128, cD / 256), blk512, LDS4, stream>>>(
      encbuf, o_wT, attn_raw, cD, cN * cH);
  k_postattn<<<dim3(cBT), blk256, 0, stream>>>(attn_raw, out, post_attn_scale, pre_ffw_scale, agbuf, hbuf);

  // ---- FFN: fused gate+up GEMM with gelu-mul epilogue, then down GEMM ----
  k_gemm8<8, 2><<<dim3(cBT / 256, (2 * cF) / 256), blk512, LDS8, stream>>>(
      hbuf, gu_wT, Gcbuf, 2 * cF, cD);
  k_gemm8<4, 0><<<dim3(cBT / 128, cD / 256), blk512, LDS4, stream>>>(
      Gcbuf, down_wT, ffw_raw, cD, cF);

  // ---- post-FFW norm/residual + AltUp correct ----
  k_final<<<dim3(cBT), blk256, 0, stream>>>(ffw_raw, agbuf, post_ffw_scale, cos_scale,
                                            router_w, corr_coefs, out);
}

// Round 10
// 961.778 us; speedup vs baseline: 1.0816x; 1.0816x over previous
//
#include <hip/hip_runtime.h>
#include <hip/hip_bf16.h>

typedef unsigned short u16;
typedef __attribute__((ext_vector_type(8))) short bf16x8_t;
typedef __attribute__((ext_vector_type(4))) float f32x4_t;

#define DEV __device__ __forceinline__

constexpr int cB = 2, cT = 2048, cD = 2048;
constexpr int cN = 8, cK = 2, cH = 256, cF = 8192;
constexpr int cBT = cB * cT;
constexpr float cEPS = 1e-6f;
constexpr float cQS = 0.0625f;     // 256^-0.5
constexpr float cCAP = 50.0f;
constexpr int cWIN = 512;
constexpr int cNH = 12;            // fused qkv heads per token: 8 q + 2 k + 2 v

DEV u16 f2bf(float f) {
  union { float f; unsigned u; } c; c.f = f;
  unsigned u = c.u;
  return (u16)((u + 0x7fffu + ((u >> 16) & 1u)) >> 16);   // RNE
}
DEV float bf2f(u16 h) {
  union { unsigned u; float f; } c; c.u = ((unsigned)h) << 16;
  return c.f;
}
DEV float g4(const float4& v, int k) { return k == 0 ? v.x : k == 1 ? v.y : k == 2 ? v.z : v.w; }
DEV void store_bf4(u16* p, float a, float b, float c, float d) {
  union { u16 h[4]; uint2 v; } o;
  o.h[0] = f2bf(a); o.h[1] = f2bf(b); o.h[2] = f2bf(c); o.h[3] = f2bf(d);
  *(uint2*)p = o.v;
}
// tanh via hardware exp+rcp: tanh(x) = 1 - 2/(e^{2x}+1). rel err ~1e-5.
DEV float tanh_fast(float x) {
  float e2 = __expf(2.0f * x);
  return 1.0f - 2.0f * __builtin_amdgcn_rcpf(e2 + 1.0f);
}
// gelu-tanh: 0.5x(1+tanh(u)) = x * (1 - 1/(e^{2u}+1))
DEV float gelu_fast(float x) {
  float u = 1.5957691216057308f * (x + 0.044715f * x * x * x);  // 2*0.7978845608
  float e2 = __expf(u);
  return x * (1.0f - __builtin_amdgcn_rcpf(e2 + 1.0f));
}

// block=256 sum reduction (4 waves)
DEV float block_sum256(float v, float* sbuf) {
  #pragma unroll
  for (int m = 32; m > 0; m >>= 1) v += __shfl_xor(v, m, 64);
  int wid = threadIdx.x >> 6;
  if ((threadIdx.x & 63) == 0) sbuf[wid] = v;
  __syncthreads();
  float tot = sbuf[0] + sbuf[1] + sbuf[2] + sbuf[3];
  __syncthreads();
  return tot;
}
// 4 values reduced with a single syncthreads round
DEV void block_sum256x4(float v[4], float* sbuf /*>=16*/) {
  #pragma unroll
  for (int m = 32; m > 0; m >>= 1) {
    #pragma unroll
    for (int k = 0; k < 4; k++) v[k] += __shfl_xor(v[k], m, 64);
  }
  int wid = threadIdx.x >> 6;
  if ((threadIdx.x & 63) == 0) *(float4*)(sbuf + wid * 4) = make_float4(v[0], v[1], v[2], v[3]);
  __syncthreads();
  #pragma unroll
  for (int k = 0; k < 4; k++) v[k] = sbuf[k] + sbuf[4 + k] + sbuf[8 + k] + sbuf[12 + k];
  __syncthreads();
}

#define GLD_LDS16(gp, lp) __builtin_amdgcn_global_load_lds( \
    (const __attribute__((address_space(1))) void*)(gp),    \
    (__attribute__((address_space(3))) void*)(lp), 16, 0, 0)

#define WAITV(n) asm volatile("s_waitcnt vmcnt(" #n ")" ::: "memory")

// ===================== weight transpose + f32->bf16 cast =====================
__global__ __launch_bounds__(256) void k_transpose_cast(
    const float* __restrict__ src, u16* __restrict__ dst, int R, int C, int gu) {
  __shared__ float tile[32][33];
  size_t base = (size_t)blockIdx.z * R * C;
  int c0 = blockIdx.x * 32, r0 = blockIdx.y * 32;
  int tx = threadIdx.x & 31, ty = threadIdx.x >> 5;
  #pragma unroll
  for (int i = 0; i < 4; i++)
    tile[ty + i * 8][tx] = src[base + (size_t)(r0 + ty + i * 8) * C + c0 + tx];
  __syncthreads();
  #pragma unroll
  for (int i = 0; i < 4; i++) {
    int c = c0 + ty + i * 8;
    int n = (gu < 0) ? c : (((c >> 4) << 5) + (gu << 4) + (c & 15));
    dst[base + (size_t)n * R + r0 + tx] = f2bf(tile[tx][ty + i * 8]);
  }
}

// ===================== RoPE sin/cos table: [BT][128] float2 =====================
__global__ __launch_bounds__(256) void k_rope_table(
    const int* __restrict__ pos, float2* __restrict__ rt) {
  int idx = blockIdx.x * 256 + threadIdx.x;    // over BT*128
  int bt = idx >> 7, j = idx & 127;
  float p = (float)pos[bt];
  float ts = powf(10000.0f, (2.0f * j) * (1.0f / cH));
  float si = p / ts;
  rt[idx] = make_float2(sinf(si), cosf(si));
}

// ===================== AltUp predict + pre-attn RMSNorm (float4) =====================
__global__ __launch_bounds__(256) void k_predict(
    const float* __restrict__ x, const float* __restrict__ router_w,
    const float* __restrict__ pred_coefs, const float* __restrict__ pre_attn_scale,
    float* __restrict__ out, u16* __restrict__ attn_in) {
  __shared__ float sbuf[16];
  int bt = blockIdx.x, tid = threadIdx.x;
  const size_t PL = (size_t)cBT * cD;
  const size_t rowb = (size_t)bt * cD;
  float4 xv[4][2];
  #pragma unroll
  for (int j = 0; j < 4; j++)
    #pragma unroll
    for (int u = 0; u < 2; u++)
      xv[j][u] = *(const float4*)(x + j * PL + rowb + (u * 256 + tid) * 4);
  float rp[4] = {0, 0, 0, 0};
  #pragma unroll
  for (int u = 0; u < 2; u++)
    #pragma unroll
    for (int k = 0; k < 4; k++) {
      int e = (u * 256 + tid) * 4 + k;
      float4 rw = *(const float4*)(router_w + (size_t)e * 4);
      float xe = g4(xv[0][u], k);
      rp[0] += xe * rw.x; rp[1] += xe * rw.y; rp[2] += xe * rw.z; rp[3] += xe * rw.w;
    }
  block_sum256x4(rp, sbuf);
  float mods[4];
  #pragma unroll
  for (int p = 0; p < 4; p++) mods[p] = tanh_fast(rp[p] * (1.0f / cD));
  float coef[4][4];
  #pragma unroll
  for (int i = 0; i < 4; i++)
    #pragma unroll
    for (int j = 0; j < 4; j++) {
      float s = 0;
      #pragma unroll
      for (int p = 0; p < 4; p++) s += mods[p] * pred_coefs[(p * 4 + i) * 4 + j];
      coef[i][j] = s;
    }
  float4 p04[2]; float ssq = 0;
  #pragma unroll
  for (int u = 0; u < 2; u++)
    #pragma unroll
    for (int i = 0; i < 4; i++) {
      float4 s = xv[i][u];
      #pragma unroll
      for (int j = 0; j < 4; j++) {
        s.x += coef[i][j] * xv[j][u].x; s.y += coef[i][j] * xv[j][u].y;
        s.z += coef[i][j] * xv[j][u].z; s.w += coef[i][j] * xv[j][u].w;
      }
      *(float4*)(out + i * PL + rowb + (u * 256 + tid) * 4) = s;
      if (i == 0) { p04[u] = s; ssq += s.x * s.x + s.y * s.y + s.z * s.z + s.w * s.w; }
    }
  float rs = rsqrtf(block_sum256(ssq, sbuf) * (1.0f / cD) + cEPS);
  #pragma unroll
  for (int u = 0; u < 2; u++) {
    int e0 = (u * 256 + tid) * 4;
    float4 sc = *(const float4*)(pre_attn_scale + e0);
    store_bf4(attn_in + rowb + e0,
              p04[u].x * rs * (1.0f + sc.x), p04[u].y * rs * (1.0f + sc.y),
              p04[u].z * rs * (1.0f + sc.z), p04[u].w * rs * (1.0f + sc.w));
  }
}

// ======== bf16 TN GEMM, MI=8 (BM=256): R8-verified 4-phase 2-buffer loop ========
// Byte-identical to the round-8 loop that passed at 301us/39% MfmaUtil.
// OUT_MODE: 1 = bf16, 2 = gelu(gate)*up, 16-col interleaved N (out Nn/2 cols)
template <int OUT_MODE>
__global__ __launch_bounds__(512, 2) void k_gemm8w(
    const u16* __restrict__ A, const u16* __restrict__ Bt, void* __restrict__ Cv,
    int Nn, int Kk) {
  constexpr int MI = 8;
  constexpr int BM = MI * 32;
  constexpr int A_KS = BM * 32;
  constexpr int B_KS = 256 * 32;
  constexpr int BUF_E = 2 * A_KS + 2 * B_KS;
  extern __shared__ u16 lds[];

  const int tid = threadIdx.x;
  const int wid = tid >> 6, lane = tid & 63;
  const int wr = wid >> 2, wc = wid & 3;
  const int fr = lane & 15, fq = lane >> 4;

  const int nwg = gridDim.x * gridDim.y;
  const int flat = blockIdx.y * gridDim.x + blockIdx.x;
  const int swz = (flat & 7) * (nwg >> 3) + (flat >> 3);
  const int m0 = (swz % gridDim.x) * BM;
  const int n0 = (swz / gridDim.x) * 256;
  const int NT = Kk >> 6;

  const int srow = lane >> 2, sslot = lane & 3;

  auto stageA = [&](int t, int ks) {
    u16* buf = lds + (t & 1) * BUF_E + ks * A_KS;
    #pragma unroll
    for (int i = 0; i < BM / 128; i++) {
      int row0 = i * 128 + wid * 16;
      int row = row0 + srow;
      int col = (sslot ^ ((row >> 1) & 3)) * 8;
      GLD_LDS16(A + (size_t)(m0 + row) * Kk + t * 64 + ks * 32 + col, buf + row0 * 32);
    }
  };
  auto stageB = [&](int t, int ks) {
    u16* buf = lds + (t & 1) * BUF_E + 2 * A_KS + ks * B_KS;
    #pragma unroll
    for (int i = 0; i < 2; i++) {
      int row0 = i * 128 + wid * 16;
      int row = row0 + srow;
      int col = (sslot ^ ((row >> 1) & 3)) * 8;
      GLD_LDS16(Bt + (size_t)(n0 + row) * Kk + t * 64 + ks * 32 + col, buf + row0 * 32);
    }
  };
  auto readA = [&](const u16* buf, int ks, int i) -> bf16x8_t {
    int row = wr * (MI * 16) + i * 16 + fr;
    return *(const bf16x8_t*)(buf + ks * A_KS + row * 32 + (fq ^ ((row >> 1) & 3)) * 8);
  };
  auto readB = [&](const u16* buf, int ks, int j) -> bf16x8_t {
    int row = wc * 64 + j * 16 + fr;
    return *(const bf16x8_t*)(buf + 2 * A_KS + ks * B_KS + row * 32 + (fq ^ ((row >> 1) & 3)) * 8);
  };

  f32x4_t acc[MI][4];
  #pragma unroll
  for (int i = 0; i < MI; i++)
    #pragma unroll
    for (int j = 0; j < 4; j++) acc[i][j] = (f32x4_t){0.f, 0.f, 0.f, 0.f};

  stageA(0, 0); stageB(0, 0); stageA(0, 1); stageB(0, 1);
  WAITV(4);
  __builtin_amdgcn_s_barrier();

#define PHASE_MFMA(J0)                                                              \
  __builtin_amdgcn_s_setprio(1);                                                    \
  _Pragma("unroll")                                                                 \
  for (int i = 0; i < MI; i++) {                                                    \
    acc[i][J0]     = __builtin_amdgcn_mfma_f32_16x16x32_bf16(a0[i], b0[0], acc[i][J0], 0, 0, 0);     \
    acc[i][J0 + 1] = __builtin_amdgcn_mfma_f32_16x16x32_bf16(a0[i], b0[1], acc[i][J0 + 1], 0, 0, 0); \
  }                                                                                 \
  __builtin_amdgcn_s_setprio(0);

  for (int t = 0; t < NT; t++) {
    const u16* buf = lds + (t & 1) * BUF_E;
    const bool pf = (t + 1 < NT);
    bf16x8_t a0[MI], b0[2];

    #pragma unroll
    for (int i = 0; i < MI; i++) a0[i] = readA(buf, 0, i);
    b0[0] = readB(buf, 0, 0); b0[1] = readB(buf, 0, 1);
    if (pf) stageA(t + 1, 0);
    __builtin_amdgcn_s_barrier();
    PHASE_MFMA(0)
    __builtin_amdgcn_s_barrier();

    b0[0] = readB(buf, 0, 2); b0[1] = readB(buf, 0, 3);
    if (pf) stageB(t + 1, 0);
    if (pf) WAITV(4); else WAITV(0);
    __builtin_amdgcn_s_barrier();
    PHASE_MFMA(2)
    __builtin_amdgcn_s_barrier();

    #pragma unroll
    for (int i = 0; i < MI; i++) a0[i] = readA(buf, 1, i);
    b0[0] = readB(buf, 1, 0); b0[1] = readB(buf, 1, 1);
    if (pf) stageA(t + 1, 1);
    __builtin_amdgcn_s_barrier();
    PHASE_MFMA(0)
    __builtin_amdgcn_s_barrier();

    b0[0] = readB(buf, 1, 2); b0[1] = readB(buf, 1, 3);
    if (pf) stageB(t + 1, 1);
    if (pf) WAITV(4);
    __builtin_amdgcn_s_barrier();
    PHASE_MFMA(2)
    __builtin_amdgcn_s_barrier();
  }
#undef PHASE_MFMA

  if constexpr (OUT_MODE == 2) {
    const int Nh = Nn >> 1;
    #pragma unroll
    for (int i = 0; i < MI; i++)
      #pragma unroll
      for (int jp = 0; jp < 2; jp++) {
        int c = (n0 + wc * 64 + jp * 32) / 2 + fr;
        #pragma unroll
        for (int r = 0; r < 4; r++) {
          int m = m0 + wr * (MI * 16) + i * 16 + fq * 4 + r;
          float g = acc[i][2 * jp][r], uu = acc[i][2 * jp + 1][r];
          ((u16*)Cv)[(size_t)m * Nh + c] = f2bf(gelu_fast(g) * uu);
        }
      }
  } else {
    #pragma unroll
    for (int i = 0; i < MI; i++)
      #pragma unroll
      for (int j = 0; j < 4; j++)
        #pragma unroll
        for (int r = 0; r < 4; r++) {
          int m = m0 + wr * (MI * 16) + i * 16 + fq * 4 + r;
          int n = n0 + wc * 64 + j * 16 + fr;
          ((u16*)Cv)[(size_t)m * Nn + n] = f2bf(acc[i][j][r]);
        }
  }
}

// ======== bf16 TN GEMM, MI=4 (BM=128): 3-slot LDS ring on the verified 4-phase skeleton ========
// Issues/tile: A0=1, B0=2, A1=1, B1=2 (6). Stage tile t+2 into slot (t+2)%3, one
// unit per phase (balanced). Waits: ph1 WAITV(9) retires A1B1(t) (6-phase coverage);
// ph3 WAITV(9) retires A0B0(t+1) (7-phase). Tails: NT-2 -> 6/3; NT-1 -> 0/skip.
// Slot-safety: slot (t+2)%3 last read in iter t-1, closed by its trailing barrier.
// OUT_MODE: 0 = f32, 1 = bf16
template <int OUT_MODE>
__global__ __launch_bounds__(512, 2) void k_gemm4r(
    const u16* __restrict__ A, const u16* __restrict__ Bt, void* __restrict__ Cv,
    int Nn, int Kk) {
  constexpr int MI = 4;
  constexpr int BM = 128;
  constexpr int A_KS = BM * 32;            // 4096 elems
  constexpr int B_KS = 256 * 32;           // 8192 elems
  constexpr int SLOT_E = 2 * A_KS + 2 * B_KS;   // 24576 elems = 48 KB
  extern __shared__ u16 lds[];             // 3 * SLOT_E

  const int tid = threadIdx.x;
  const int wid = tid >> 6, lane = tid & 63;
  const int wr = wid >> 2, wc = wid & 3;
  const int fr = lane & 15, fq = lane >> 4;

  const int nwg = gridDim.x * gridDim.y;
  const int flat = blockIdx.y * gridDim.x + blockIdx.x;
  const int swz = (flat & 7) * (nwg >> 3) + (flat >> 3);
  const int m0 = (swz % gridDim.x) * BM;
  const int n0 = (swz / gridDim.x) * 256;
  const int NT = Kk >> 6;

  const int srow = lane >> 2, sslot = lane & 3;

  auto stageA = [&](int t, int ks) {
    u16* buf = lds + (t % 3) * SLOT_E + ks * A_KS;
    int row0 = wid * 16;
    int row = row0 + srow;
    int col = (sslot ^ ((row >> 1) & 3)) * 8;
    GLD_LDS16(A + (size_t)(m0 + row) * Kk + t * 64 + ks * 32 + col, buf + row0 * 32);
  };
  auto stageB = [&](int t, int ks) {
    u16* buf = lds + (t % 3) * SLOT_E + 2 * A_KS + ks * B_KS;
    #pragma unroll
    for (int i = 0; i < 2; i++) {
      int row0 = i * 128 + wid * 16;
      int row = row0 + srow;
      int col = (sslot ^ ((row >> 1) & 3)) * 8;
      GLD_LDS16(Bt + (size_t)(n0 + row) * Kk + t * 64 + ks * 32 + col, buf + row0 * 32);
    }
  };
  auto readA = [&](const u16* buf, int ks, int i) -> bf16x8_t {
    int row = wr * 64 + i * 16 + fr;
    return *(const bf16x8_t*)(buf + ks * A_KS + row * 32 + (fq ^ ((row >> 1) & 3)) * 8);
  };
  auto readB = [&](const u16* buf, int ks, int j) -> bf16x8_t {
    int row = wc * 64 + j * 16 + fr;
    return *(const bf16x8_t*)(buf + 2 * A_KS + ks * B_KS + row * 32 + (fq ^ ((row >> 1) & 3)) * 8);
  };

  f32x4_t acc[MI][4];
  #pragma unroll
  for (int i = 0; i < MI; i++)
    #pragma unroll
    for (int j = 0; j < 4; j++) acc[i][j] = (f32x4_t){0.f, 0.f, 0.f, 0.f};

  // prologue: stage tiles 0 and 1 fully (12 issues); retire A0B0(0)
  stageA(0, 0); stageB(0, 0); stageA(0, 1); stageB(0, 1);
  stageA(1, 0); stageB(1, 0); stageA(1, 1); stageB(1, 1);
  WAITV(9);
  __builtin_amdgcn_s_barrier();

#define PHASE_MFMA4(J0)                                                             \
  __builtin_amdgcn_s_setprio(1);                                                    \
  _Pragma("unroll")                                                                 \
  for (int i = 0; i < MI; i++) {                                                    \
    acc[i][J0]     = __builtin_amdgcn_mfma_f32_16x16x32_bf16(a0[i], b0[0], acc[i][J0], 0, 0, 0);     \
    acc[i][J0 + 1] = __builtin_amdgcn_mfma_f32_16x16x32_bf16(a0[i], b0[1], acc[i][J0 + 1], 0, 0, 0); \
  }                                                                                 \
  __builtin_amdgcn_s_setprio(0);

  for (int t = 0; t < NT; t++) {
    const u16* buf = lds + (t % 3) * SLOT_E;
    const bool pf2 = (t + 2 < NT);
    const bool pf1 = (t + 1 < NT);
    bf16x8_t a0[MI], b0[2];

    // ---- phase 0: ks=0, n-frags 0,1 ; stage A0(t+2)
    #pragma unroll
    for (int i = 0; i < MI; i++) a0[i] = readA(buf, 0, i);
    b0[0] = readB(buf, 0, 0); b0[1] = readB(buf, 0, 1);
    if (pf2) stageA(t + 2, 0);
    __builtin_amdgcn_s_barrier();
    PHASE_MFMA4(0)
    __builtin_amdgcn_s_barrier();

    // ---- phase 1: ks=0, n-frags 2,3 ; stage B0(t+2); retire A1B1(t)
    b0[0] = readB(buf, 0, 2); b0[1] = readB(buf, 0, 3);
    if (pf2) stageB(t + 2, 0);
    if (pf2) WAITV(9); else if (pf1) WAITV(6); else WAITV(0);
    __builtin_amdgcn_s_barrier();
    PHASE_MFMA4(2)
    __builtin_amdgcn_s_barrier();

    // ---- phase 2: ks=1, n-frags 0,1 ; stage A1(t+2)
    #pragma unroll
    for (int i = 0; i < MI; i++) a0[i] = readA(buf, 1, i);
    b0[0] = readB(buf, 1, 0); b0[1] = readB(buf, 1, 1);
    if (pf2) stageA(t + 2, 1);
    __builtin_amdgcn_s_barrier();
    PHASE_MFMA4(0)
    __builtin_amdgcn_s_barrier();

    // ---- phase 3: ks=1, n-frags 2,3 ; stage B1(t+2); retire A0B0(t+1)
    b0[0] = readB(buf, 1, 2); b0[1] = readB(buf, 1, 3);
    if (pf2) stageB(t + 2, 1);
    if (pf2) WAITV(9); else if (pf1) WAITV(3);
    __builtin_amdgcn_s_barrier();
    PHASE_MFMA4(2)
    __builtin_amdgcn_s_barrier();
  }
#undef PHASE_MFMA4

  #pragma unroll
  for (int i = 0; i < MI; i++)
    #pragma unroll
    for (int j = 0; j < 4; j++)
      #pragma unroll
      for (int r = 0; r < 4; r++) {
        int m = m0 + wr * 64 + i * 16 + fq * 4 + r;
        int n = n0 + wc * 64 + j * 16 + fr;
        float v = acc[i][j][r];
        if (OUT_MODE == 1) ((u16*)Cv)[(size_t)m * Nn + n] = f2bf(v);
        else ((float*)Cv)[(size_t)m * Nn + n] = v;
      }
}

// ===== fused QKV post: q/k RMSNorm+RoPE (table), v RMSNorm+transpose — one kernel =====
__global__ __launch_bounds__(64) void k_qkvpost(
    u16* __restrict__ qkv, const float* __restrict__ qscale,
    const float* __restrict__ kscale, const float2* __restrict__ rt,
    u16* __restrict__ vT) {
  int h = blockIdx.x % cNH, bt = blockIdx.x / cNH;
  int lane = threadIdx.x;
  u16* row = qkv + ((size_t)bt * cNH + h) * cH;
  float v[4], ssq = 0;
  #pragma unroll
  for (int m = 0; m < 4; m++) { v[m] = bf2f(row[lane + 64 * m]); ssq += v[m] * v[m]; }
  #pragma unroll
  for (int mm = 32; mm > 0; mm >>= 1) ssq += __shfl_xor(ssq, mm, 64);
  float rs = rsqrtf(ssq * (1.0f / cH) + cEPS);
  if (h < 10) {
    const float* sc = (h < 8) ? qscale : kscale;
    float os = (h < 8) ? cQS : 1.0f;
    #pragma unroll
    for (int m = 0; m < 4; m++) {
      int e = lane + 64 * m;
      v[m] = v[m] * rs * (1.0f + sc[e]);
    }
    #pragma unroll
    for (int m = 0; m < 2; m++) {
      int j = lane + 64 * m;
      float2 t = rt[bt * 128 + j];          // (sin, cos)
      float x1 = v[m], x2 = v[m + 2];
      row[j]       = f2bf((x1 * t.y - x2 * t.x) * os);
      row[j + 128] = f2bf((x2 * t.y + x1 * t.x) * os);
    }
  } else {
    int kk = h - 10;
    int b = bt / cT, t = bt % cT;
    #pragma unroll
    for (int m = 0; m < 4; m++) {
      int e = lane + 64 * m;
      vT[((size_t)(b * cK + kk) * cH + e) * cT + t] = f2bf(v[m] * rs);
    }
  }
}

// ===================== sliding-window GQA attention, 1 wave / 16-row Q tile =====================
__global__ __launch_bounds__(64) void k_attn(
    const u16* __restrict__ qkv, const u16* __restrict__ vT, u16* __restrict__ enc) {
  int t0 = blockIdx.x * 16;
  int n = blockIdx.y, b = blockIdx.z;
  int kn = n >> 2;                           // GQA group of 4
  int lane = threadIdx.x;
  int fr = lane & 15, fq = lane >> 4;
  __shared__ float P[16][33];                // +1 pad: kills 32-way conflict on transpose read

  bf16x8_t qf[8];
  const u16* qrow = qkv + ((size_t)(b * cT + t0 + fr) * cNH + n) * cH;
  #pragma unroll
  for (int ks = 0; ks < 8; ks++) qf[ks] = *(const bf16x8_t*)(qrow + ks * 32 + fq * 8);

  f32x4_t acc[16];
  #pragma unroll
  for (int ht = 0; ht < 16; ht++) acc[ht] = (f32x4_t){0.f, 0.f, 0.f, 0.f};
  float psum[4] = {0.f, 0.f, 0.f, 0.f};

  int s_lo = t0 - (cWIN - 1); if (s_lo < 0) s_lo = 0; s_lo &= ~31;
  for (int s0 = s_lo; s0 <= t0 + 15; s0 += 32) {
    f32x4_t S[2];
    S[0] = (f32x4_t){0.f, 0.f, 0.f, 0.f};
    S[1] = (f32x4_t){0.f, 0.f, 0.f, 0.f};
    #pragma unroll
    for (int c = 0; c < 2; c++) {
      const u16* krow = qkv + ((size_t)(b * cT + s0 + c * 16 + fr) * cNH + 8 + kn) * cH;
      #pragma unroll
      for (int ks = 0; ks < 8; ks++) {
        bf16x8_t kf = *(const bf16x8_t*)(krow + ks * 32 + fq * 8);
        S[c] = __builtin_amdgcn_mfma_f32_16x16x32_bf16(qf[ks], kf, S[c], 0, 0, 0);
      }
    }
    // soft-cap (fast tanh), mask, exp (fixed-max softmax: cap bounds logits to [-50,50])
    #pragma unroll
    for (int c = 0; c < 2; c++) {
      int s = s0 + c * 16 + fr;
      #pragma unroll
      for (int r = 0; r < 4; r++) {
        int t = t0 + fq * 4 + r;
        float l = cCAP * tanh_fast(S[c][r] * (1.0f / cCAP));
        float pe = (s <= t && s >= t - (cWIN - 1)) ? __expf(l) : 0.0f;
        psum[r] += pe;
        P[fq * 4 + r][c * 16 + fr] = pe;
      }
    }
    // transpose P via LDS into A-fragment layout (single wave: ds ops in order)
    bf16x8_t pf;
    #pragma unroll
    for (int e = 0; e < 8; e++) pf[e] = (short)f2bf(P[fr][fq * 8 + e]);
    #pragma unroll
    for (int ht = 0; ht < 16; ht++) {
      bf16x8_t vf = *(const bf16x8_t*)(vT + (((size_t)(b * cK + kn)) * cH + ht * 16 + fr) * cT + s0 + fq * 8);
      acc[ht] = __builtin_amdgcn_mfma_f32_16x16x32_bf16(pf, vf, acc[ht], 0, 0, 0);
    }
  }
  #pragma unroll
  for (int r = 0; r < 4; r++) {
    #pragma unroll
    for (int m = 1; m < 16; m <<= 1) psum[r] += __shfl_xor(psum[r], m, 64);
  }
  float inv[4];
  #pragma unroll
  for (int r = 0; r < 4; r++) inv[r] = 1.0f / psum[r];
  #pragma unroll
  for (int ht = 0; ht < 16; ht++)
    #pragma unroll
    for (int r = 0; r < 4; r++)
      enc[(((size_t)(b * cT + t0 + fq * 4 + r)) * cN + n) * cH + ht * 16 + fr] =
          f2bf(acc[ht][r] * inv[r]);
}

// ===================== post-attn: norm + residual + pre-FFW norm (float4) =====================
__global__ __launch_bounds__(256) void k_postattn(
    const float* __restrict__ attn_raw, const float* __restrict__ out0,
    const float* __restrict__ post_attn_scale, const float* __restrict__ pre_ffw_scale,
    float* __restrict__ ag, u16* __restrict__ h) {
  __shared__ float sbuf[4];
  int bt = blockIdx.x, tid = threadIdx.x;
  const size_t rowb = (size_t)bt * cD;
  float4 ar[2]; float ssq = 0;
  #pragma unroll
  for (int u = 0; u < 2; u++) {
    ar[u] = *(const float4*)(attn_raw + rowb + (u * 256 + tid) * 4);
    ssq += ar[u].x * ar[u].x + ar[u].y * ar[u].y + ar[u].z * ar[u].z + ar[u].w * ar[u].w;
  }
  float rs = rsqrtf(block_sum256(ssq, sbuf) * (1.0f / cD) + cEPS);
  float4 agv[2]; float ssq2 = 0;
  #pragma unroll
  for (int u = 0; u < 2; u++) {
    int e0 = (u * 256 + tid) * 4;
    float4 o0 = *(const float4*)(out0 + rowb + e0);
    float4 sc = *(const float4*)(post_attn_scale + e0);
    float4 a;
    a.x = o0.x + ar[u].x * rs * (1.0f + sc.x);
    a.y = o0.y + ar[u].y * rs * (1.0f + sc.y);
    a.z = o0.z + ar[u].z * rs * (1.0f + sc.z);
    a.w = o0.w + ar[u].w * rs * (1.0f + sc.w);
    agv[u] = a;
    *(float4*)(ag + rowb + e0) = a;
    ssq2 += a.x * a.x + a.y * a.y + a.z * a.z + a.w * a.w;
  }
  float rs2 = rsqrtf(block_sum256(ssq2, sbuf) * (1.0f / cD) + cEPS);
  #pragma unroll
  for (int u = 0; u < 2; u++) {
    int e0 = (u * 256 + tid) * 4;
    float4 sc = *(const float4*)(pre_ffw_scale + e0);
    store_bf4(h + rowb + e0,
              agv[u].x * rs2 * (1.0f + sc.x), agv[u].y * rs2 * (1.0f + sc.y),
              agv[u].z * rs2 * (1.0f + sc.z), agv[u].w * rs2 * (1.0f + sc.w));
  }
}

// ======= post-FFW norm + residual + AltUp correct, in-place on out (float4) =======
__global__ __launch_bounds__(256) void k_final(
    const float* __restrict__ ffw_raw, const float* __restrict__ ag,
    const float* __restrict__ post_ffw_scale, const float* __restrict__ cos_scale,
    const float* __restrict__ router_w, const float* __restrict__ corr_coefs,
    float* __restrict__ out) {
  __shared__ float sbuf[16];
  int bt = blockIdx.x, tid = threadIdx.x;
  const size_t PL = (size_t)cBT * cD;
  const size_t rowb = (size_t)bt * cD;
  float4 fv[2]; float ssq = 0;
  #pragma unroll
  for (int u = 0; u < 2; u++) {
    fv[u] = *(const float4*)(ffw_raw + rowb + (u * 256 + tid) * 4);
    ssq += fv[u].x * fv[u].x + fv[u].y * fv[u].y + fv[u].z * fv[u].z + fv[u].w * fv[u].w;
  }
  float rs = rsqrtf(block_sum256(ssq, sbuf) * (1.0f / cD) + cEPS);
  float4 av[2];
  float rp[4] = {0, 0, 0, 0};
  #pragma unroll
  for (int u = 0; u < 2; u++) {
    int e0 = (u * 256 + tid) * 4;
    float4 agx = *(const float4*)(ag + rowb + e0);
    float4 ps = *(const float4*)(post_ffw_scale + e0);
    float4 cs = *(const float4*)(cos_scale + e0);
    float4 a;
    a.x = (agx.x + fv[u].x * rs * (1.0f + ps.x)) * cs.x;
    a.y = (agx.y + fv[u].y * rs * (1.0f + ps.y)) * cs.y;
    a.z = (agx.z + fv[u].z * rs * (1.0f + ps.z)) * cs.z;
    a.w = (agx.w + fv[u].w * rs * (1.0f + ps.w)) * cs.w;
    av[u] = a;
    #pragma unroll
    for (int k = 0; k < 4; k++) {
      float4 rw = *(const float4*)(router_w + (size_t)(e0 + k) * 4);
      float xe = g4(a, k);
      rp[0] += xe * rw.x; rp[1] += xe * rw.y; rp[2] += xe * rw.z; rp[3] += xe * rw.w;
    }
  }
  block_sum256x4(rp, sbuf);
  float cc[4];
  #pragma unroll
  for (int i = 0; i < 4; i++) {
    float s = 1.0f;
    #pragma unroll
    for (int p = 0; p < 4; p++) s += tanh_fast(rp[p] * (1.0f / cD)) * corr_coefs[p * 4 + i];
    cc[i] = s;
  }
  #pragma unroll
  for (int u = 0; u < 2; u++) {
    size_t o = rowb + (u * 256 + tid) * 4;
    float4 p0 = *(const float4*)(out + o);
    float4 in4;
    in4.x = av[u].x - p0.x; in4.y = av[u].y - p0.y;
    in4.z = av[u].z - p0.z; in4.w = av[u].w - p0.w;
    float4 w0;
    w0.x = p0.x + cc[0] * in4.x; w0.y = p0.y + cc[0] * in4.y;
    w0.z = p0.z + cc[0] * in4.z; w0.w = p0.w + cc[0] * in4.w;
    *(float4*)(out + o) = w0;
    #pragma unroll
    for (int i = 1; i < 4; i++) {
      float4 q = *(const float4*)(out + i * PL + o);
      q.x += cc[i] * in4.x; q.y += cc[i] * in4.y;
      q.z += cc[i] * in4.z; q.w += cc[i] * in4.w;
      *(float4*)(out + i * PL + o) = q;
    }
  }
}

// =============================================================================
extern "C" void kernel_launch(void* const* d_in, const int* in_sizes, int n_in,
                              void* d_out, int out_size, void* d_ws, size_t ws_size,
                              hipStream_t stream) {
  const float* x              = (const float*)d_in[0];
  const int*   pos            = (const int*)d_in[1];
  // d_in[2] attn_mask: equals causal(pos) — recomputed from positions in-kernel
  const float* router_w       = (const float*)d_in[3];
  const float* pred_coefs     = (const float*)d_in[4];
  const float* corr_coefs     = (const float*)d_in[5];
  const float* cos_scale      = (const float*)d_in[6];
  const float* pre_attn_scale = (const float*)d_in[7];
  const float* q_w            = (const float*)d_in[8];
  const float* kv_w           = (const float*)d_in[9];
  const float* qk_q_scale     = (const float*)d_in[10];
  const float* qk_k_scale     = (const float*)d_in[11];
  const float* o_w            = (const float*)d_in[12];
  const float* post_attn_scale= (const float*)d_in[13];
  const float* pre_ffw_scale  = (const float*)d_in[14];
  const float* gate_w         = (const float*)d_in[15];
  const float* up_w           = (const float*)d_in[16];
  const float* down_w         = (const float*)d_in[17];
  const float* post_ffw_scale = (const float*)d_in[18];
  float* out = (float*)d_out;

  char* wsp = (char*)d_ws;
  size_t off = 0;
  auto take = [&](size_t nbytes) -> char* {
    char* p = wsp + off;
    off += (nbytes + 255) & ~((size_t)255);
    return p;
  };
  u16* gu_wT    = (u16*)take((size_t)2 * cF * cD * 2);          // [16384][2048], 16-col interleave
  u16* down_wT  = (u16*)take((size_t)cD * cF * 2);              // [2048][8192]
  u16* qkv_wT   = (u16*)take((size_t)cNH * cH * cD * 2);        // [3072][2048]
  u16* o_wT     = (u16*)take((size_t)cD * cN * cH * 2);         // [2048][2048]
  u16* attn_in  = (u16*)take((size_t)cBT * cD * 2);
  u16* qkvbuf   = (u16*)take((size_t)cBT * cNH * cH * 2);       // [BT][3072]
  u16* vTbuf    = (u16*)take((size_t)cB * cK * cH * cT * 2);
  u16* encbuf   = (u16*)take((size_t)cBT * cN * cH * 2);
  float* attn_raw = (float*)take((size_t)cBT * cD * 4);
  float* agbuf    = (float*)take((size_t)cBT * cD * 4);
  u16* hbuf     = (u16*)take((size_t)cBT * cD * 2);
  u16* Gcbuf    = (u16*)take((size_t)cBT * cF * 2);             // gelu(G)*U, [BT][8192]
  float* ffw_raw = (float*)take((size_t)cBT * cD * 4);
  float2* ropetab = (float2*)take((size_t)cBT * 128 * 8);
  (void)in_sizes; (void)n_in; (void)out_size; (void)ws_size;

  dim3 blk256(256), blk64(64), blk512(512);
  constexpr unsigned LDS8  = 2 * (2 * 256 * 32 + 2 * 256 * 32) * 2;   // 128 KiB
  constexpr unsigned LDS4R = 3 * (2 * 128 * 32 + 2 * 256 * 32) * 2;   // 144 KiB

  // ---- weight prep: transpose + cast to bf16 (TN layout); gate/up 16-col interleaved ----
  k_transpose_cast<<<dim3(cF / 32, cD / 32, 1), blk256, 0, stream>>>(gate_w, gu_wT, cD, cF, 0);
  k_transpose_cast<<<dim3(cF / 32, cD / 32, 1), blk256, 0, stream>>>(up_w, gu_wT, cD, cF, 1);
  k_transpose_cast<<<dim3(cD / 32, cF / 32, 1), blk256, 0, stream>>>(down_w, down_wT, cF, cD, -1);
  k_transpose_cast<<<dim3(cH / 32, cD / 32, cN), blk256, 0, stream>>>(q_w, qkv_wT, cD, cH, -1);
  k_transpose_cast<<<dim3(cH / 32, cD / 32, 2 * cK), blk256, 0, stream>>>(
      kv_w, qkv_wT + (size_t)cN * cH * cD, cD, cH, -1);
  k_transpose_cast<<<dim3(cD / 32, (cN * cH) / 32, 1), blk256, 0, stream>>>(o_w, o_wT, cN * cH, cD, -1);
  k_rope_table<<<dim3(cBT * 128 / 256), blk256, 0, stream>>>(pos, ropetab);

  // ---- AltUp predict (writes predictions into d_out) + pre-attn RMSNorm ----
  k_predict<<<dim3(cBT), blk256, 0, stream>>>(x, router_w, pred_coefs, pre_attn_scale, out, attn_in);

  // ---- fused QKV projection: [4096,2048] x [3072,2048]^T ----
  k_gemm4r<1><<<dim3(cBT / 128, (cNH * cH) / 256), blk512, LDS4R, stream>>>(
      attn_in, qkv_wT, qkvbuf, cNH * cH, cD);

  // ---- fused QK-norm+RoPE / V-norm+transpose ----
  k_qkvpost<<<dim3(cBT * cNH), blk64, 0, stream>>>(qkvbuf, qk_q_scale, qk_k_scale, ropetab, vTbuf);

  // ---- sliding-window attention ----
  k_attn<<<dim3(cT / 16, cN, cB), blk64, 0, stream>>>(qkvbuf, vTbuf, encbuf);

  // ---- O projection + post-attn norm/residual + pre-FFW norm ----
  k_gemm4r<0><<<dim3(cBT / 128, cD / 256), blk512, LDS4R, stream>>>(
      encbuf, o_wT, attn_raw, cD, cN * cH);
  k_postattn<<<dim3(cBT), blk256, 0, stream>>>(attn_raw, out, post_attn_scale, pre_ffw_scale, agbuf, hbuf);

  // ---- FFN: fused gate+up GEMM (MI=8, R8-verified) with gelu-mul epilogue, then down GEMM ----
  k_gemm8w<2><<<dim3(cBT / 256, (2 * cF) / 256), blk512, LDS8, stream>>>(
      hbuf, gu_wT, Gcbuf, 2 * cF, cD);
  k_gemm4r<0><<<dim3(cBT / 128, cD / 256), blk512, LDS4R, stream>>>(
      Gcbuf, down_wT, ffw_raw, cD, cF);

  // ---- post-FFW norm/residual + AltUp correct ----
  k_final<<<dim3(cBT), blk256, 0, stream>>>(ffw_raw, agbuf, post_ffw_scale, cos_scale,
                                            router_w, corr_coefs, out);
}

// Round 11
// 950.617 us; speedup vs baseline: 1.0943x; 1.0117x over previous
//
#include <hip/hip_runtime.h>
#include <hip/hip_bf16.h>

typedef unsigned short u16;
typedef __attribute__((ext_vector_type(8))) short bf16x8_t;
typedef __attribute__((ext_vector_type(4))) float f32x4_t;

#define DEV __device__ __forceinline__

constexpr int cB = 2, cT = 2048, cD = 2048;
constexpr int cN = 8, cK = 2, cH = 256, cF = 8192;
constexpr int cBT = cB * cT;
constexpr float cEPS = 1e-6f;
constexpr float cQS = 0.0625f;     // 256^-0.5
constexpr float cCAP = 50.0f;
constexpr int cWIN = 512;
constexpr int cNH = 12;            // fused qkv heads per token: 8 q + 2 k + 2 v

DEV u16 f2bf(float f) {
  union { float f; unsigned u; } c; c.f = f;
  unsigned u = c.u;
  return (u16)((u + 0x7fffu + ((u >> 16) & 1u)) >> 16);   // RNE
}
DEV float bf2f(u16 h) {
  union { unsigned u; float f; } c; c.u = ((unsigned)h) << 16;
  return c.f;
}
DEV float g4(const float4& v, int k) { return k == 0 ? v.x : k == 1 ? v.y : k == 2 ? v.z : v.w; }
DEV void store_bf4(u16* p, float a, float b, float c, float d) {
  union { u16 h[4]; uint2 v; } o;
  o.h[0] = f2bf(a); o.h[1] = f2bf(b); o.h[2] = f2bf(c); o.h[3] = f2bf(d);
  *(uint2*)p = o.v;
}
// tanh via hardware exp+rcp: tanh(x) = 1 - 2/(e^{2x}+1). rel err ~1e-5.
DEV float tanh_fast(float x) {
  float e2 = __expf(2.0f * x);
  return 1.0f - 2.0f * __builtin_amdgcn_rcpf(e2 + 1.0f);
}
// gelu-tanh: 0.5x(1+tanh(u)) = x * (1 - 1/(e^{2u}+1))
DEV float gelu_fast(float x) {
  float u = 1.5957691216057308f * (x + 0.044715f * x * x * x);  // 2*0.7978845608
  float e2 = __expf(u);
  return x * (1.0f - __builtin_amdgcn_rcpf(e2 + 1.0f));
}

// block=256 sum reduction (4 waves)
DEV float block_sum256(float v, float* sbuf) {
  #pragma unroll
  for (int m = 32; m > 0; m >>= 1) v += __shfl_xor(v, m, 64);
  int wid = threadIdx.x >> 6;
  if ((threadIdx.x & 63) == 0) sbuf[wid] = v;
  __syncthreads();
  float tot = sbuf[0] + sbuf[1] + sbuf[2] + sbuf[3];
  __syncthreads();
  return tot;
}
// 4 values reduced with a single syncthreads round
DEV void block_sum256x4(float v[4], float* sbuf /*>=16*/) {
  #pragma unroll
  for (int m = 32; m > 0; m >>= 1) {
    #pragma unroll
    for (int k = 0; k < 4; k++) v[k] += __shfl_xor(v[k], m, 64);
  }
  int wid = threadIdx.x >> 6;
  if ((threadIdx.x & 63) == 0) *(float4*)(sbuf + wid * 4) = make_float4(v[0], v[1], v[2], v[3]);
  __syncthreads();
  #pragma unroll
  for (int k = 0; k < 4; k++) v[k] = sbuf[k] + sbuf[4 + k] + sbuf[8 + k] + sbuf[12 + k];
  __syncthreads();
}

#define GLD_LDS16(gp, lp) __builtin_amdgcn_global_load_lds( \
    (const __attribute__((address_space(1))) void*)(gp),    \
    (__attribute__((address_space(3))) void*)(lp), 16, 0, 0)

#define WAITV(n) asm volatile("s_waitcnt vmcnt(" #n ")" ::: "memory")

// ============= weight transpose + f32->bf16 cast, 64x64 tiles, vectorized =============
// src: [batch, R, C] f32 -> dst row n(c): identity (gu<0) or gate/up 16-col interleave
__global__ __launch_bounds__(256) void k_transpose_cast(
    const float* __restrict__ src, u16* __restrict__ dst, int R, int C, int gu) {
  __shared__ float tile[64][65];
  size_t base = (size_t)blockIdx.z * R * C;
  int c0 = blockIdx.x * 64, r0 = blockIdx.y * 64;
  int tx = threadIdx.x & 15, ty = threadIdx.x >> 4;     // 16 x 16
  #pragma unroll
  for (int i = 0; i < 4; i++) {
    int r = ty + i * 16;
    float4 v = *(const float4*)(src + base + (size_t)(r0 + r) * C + c0 + tx * 4);
    tile[r][tx * 4 + 0] = v.x; tile[r][tx * 4 + 1] = v.y;
    tile[r][tx * 4 + 2] = v.z; tile[r][tx * 4 + 3] = v.w;
  }
  __syncthreads();
  #pragma unroll
  for (int i = 0; i < 4; i++) {
    int j = ty + i * 16;
    int c = c0 + j;
    int n = (gu < 0) ? c : (((c >> 4) << 5) + (gu << 4) + (c & 15));
    store_bf4(dst + base + (size_t)n * R + r0 + tx * 4,
              tile[tx * 4 + 0][j], tile[tx * 4 + 1][j],
              tile[tx * 4 + 2][j], tile[tx * 4 + 3][j]);
  }
}

// ===================== RoPE sin/cos table: [BT][128] float2 =====================
__global__ __launch_bounds__(256) void k_rope_table(
    const int* __restrict__ pos, float2* __restrict__ rt) {
  int idx = blockIdx.x * 256 + threadIdx.x;    // over BT*128
  int bt = idx >> 7, j = idx & 127;
  float p = (float)pos[bt];
  float ts = powf(10000.0f, (2.0f * j) * (1.0f / cH));
  float si = p / ts;
  rt[idx] = make_float2(sinf(si), cosf(si));
}

// ===================== AltUp predict + pre-attn RMSNorm (float4) =====================
__global__ __launch_bounds__(256) void k_predict(
    const float* __restrict__ x, const float* __restrict__ router_w,
    const float* __restrict__ pred_coefs, const float* __restrict__ pre_attn_scale,
    float* __restrict__ out, u16* __restrict__ attn_in) {
  __shared__ float sbuf[16];
  int bt = blockIdx.x, tid = threadIdx.x;
  const size_t PL = (size_t)cBT * cD;
  const size_t rowb = (size_t)bt * cD;
  float4 xv[4][2];
  #pragma unroll
  for (int j = 0; j < 4; j++)
    #pragma unroll
    for (int u = 0; u < 2; u++)
      xv[j][u] = *(const float4*)(x + j * PL + rowb + (u * 256 + tid) * 4);
  float rp[4] = {0, 0, 0, 0};
  #pragma unroll
  for (int u = 0; u < 2; u++)
    #pragma unroll
    for (int k = 0; k < 4; k++) {
      int e = (u * 256 + tid) * 4 + k;
      float4 rw = *(const float4*)(router_w + (size_t)e * 4);
      float xe = g4(xv[0][u], k);
      rp[0] += xe * rw.x; rp[1] += xe * rw.y; rp[2] += xe * rw.z; rp[3] += xe * rw.w;
    }
  block_sum256x4(rp, sbuf);
  float mods[4];
  #pragma unroll
  for (int p = 0; p < 4; p++) mods[p] = tanh_fast(rp[p] * (1.0f / cD));
  float coef[4][4];
  #pragma unroll
  for (int i = 0; i < 4; i++)
    #pragma unroll
    for (int j = 0; j < 4; j++) {
      float s = 0;
      #pragma unroll
      for (int p = 0; p < 4; p++) s += mods[p] * pred_coefs[(p * 4 + i) * 4 + j];
      coef[i][j] = s;
    }
  float4 p04[2]; float ssq = 0;
  #pragma unroll
  for (int u = 0; u < 2; u++)
    #pragma unroll
    for (int i = 0; i < 4; i++) {
      float4 s = xv[i][u];
      #pragma unroll
      for (int j = 0; j < 4; j++) {
        s.x += coef[i][j] * xv[j][u].x; s.y += coef[i][j] * xv[j][u].y;
        s.z += coef[i][j] * xv[j][u].z; s.w += coef[i][j] * xv[j][u].w;
      }
      *(float4*)(out + i * PL + rowb + (u * 256 + tid) * 4) = s;
      if (i == 0) { p04[u] = s; ssq += s.x * s.x + s.y * s.y + s.z * s.z + s.w * s.w; }
    }
  float rs = rsqrtf(block_sum256(ssq, sbuf) * (1.0f / cD) + cEPS);
  #pragma unroll
  for (int u = 0; u < 2; u++) {
    int e0 = (u * 256 + tid) * 4;
    float4 sc = *(const float4*)(pre_attn_scale + e0);
    store_bf4(attn_in + rowb + e0,
              p04[u].x * rs * (1.0f + sc.x), p04[u].y * rs * (1.0f + sc.y),
              p04[u].z * rs * (1.0f + sc.z), p04[u].w * rs * (1.0f + sc.w));
  }
}

// ======== bf16 TN GEMM, MI=8 (BM=256): R8-verified skeleton + half-tile-shifted staging ========
// LDS addressing (t&1)*BUF + ks*A_KS is a 4-half-slot ring: slot(h)=(2t+ks)&3.
// R11: stage targets shifted 1 half-tile deeper (ph0->A1(t+1), ph1->B1(t+1),
// ph2->A0(t+2), ph3->B0(t+2)); waits stay at ph1/ph3 retiring with vmcnt(8)
// (12 in flight - 4). Coverage: half h issued at global phase 2h-6/2h-5, waited
// at 2h-1 -> 4-5 phases (was 2-3). Slot-safety: write to slot (2t+3)&3 issues
// after trailing barrier of its last reader (half 2t-1, ph3(t-1)); write to
// (2t+4)&3=(2t)&3 issues at ph2 after ph1's trailing barrier closes half-2t
// reads. Tails: t=NT-2 -> ph1 vmcnt(8), ph3 vmcnt(4); t=NT-1 -> ph1 vmcnt(0).
// Issue balance unchanged: 2 issues/phase (R9's bunching regression avoided).
// OUT_MODE: 1 = bf16, 2 = gelu(gate)*up, 16-col interleaved N (out Nn/2 cols)
template <int OUT_MODE>
__global__ __launch_bounds__(512, 2) void k_gemm8w(
    const u16* __restrict__ A, const u16* __restrict__ Bt, void* __restrict__ Cv,
    int Nn, int Kk) {
  constexpr int MI = 8;
  constexpr int BM = MI * 32;
  constexpr int A_KS = BM * 32;
  constexpr int B_KS = 256 * 32;
  constexpr int BUF_E = 2 * A_KS + 2 * B_KS;
  extern __shared__ u16 lds[];

  const int tid = threadIdx.x;
  const int wid = tid >> 6, lane = tid & 63;
  const int wr = wid >> 2, wc = wid & 3;
  const int fr = lane & 15, fq = lane >> 4;

  const int nwg = gridDim.x * gridDim.y;
  const int flat = blockIdx.y * gridDim.x + blockIdx.x;
  const int swz = (flat & 7) * (nwg >> 3) + (flat >> 3);
  const int m0 = (swz % gridDim.x) * BM;
  const int n0 = (swz / gridDim.x) * 256;
  const int NT = Kk >> 6;

  const int srow = lane >> 2, sslot = lane & 3;

  auto stageA = [&](int t, int ks) {
    u16* buf = lds + (t & 1) * BUF_E + ks * A_KS;
    #pragma unroll
    for (int i = 0; i < BM / 128; i++) {
      int row0 = i * 128 + wid * 16;
      int row = row0 + srow;
      int col = (sslot ^ ((row >> 1) & 3)) * 8;
      GLD_LDS16(A + (size_t)(m0 + row) * Kk + t * 64 + ks * 32 + col, buf + row0 * 32);
    }
  };
  auto stageB = [&](int t, int ks) {
    u16* buf = lds + (t & 1) * BUF_E + 2 * A_KS + ks * B_KS;
    #pragma unroll
    for (int i = 0; i < 2; i++) {
      int row0 = i * 128 + wid * 16;
      int row = row0 + srow;
      int col = (sslot ^ ((row >> 1) & 3)) * 8;
      GLD_LDS16(Bt + (size_t)(n0 + row) * Kk + t * 64 + ks * 32 + col, buf + row0 * 32);
    }
  };
  auto readA = [&](const u16* buf, int ks, int i) -> bf16x8_t {
    int row = wr * (MI * 16) + i * 16 + fr;
    return *(const bf16x8_t*)(buf + ks * A_KS + row * 32 + (fq ^ ((row >> 1) & 3)) * 8);
  };
  auto readB = [&](const u16* buf, int ks, int j) -> bf16x8_t {
    int row = wc * 64 + j * 16 + fr;
    return *(const bf16x8_t*)(buf + 2 * A_KS + ks * B_KS + row * 32 + (fq ^ ((row >> 1) & 3)) * 8);
  };

  f32x4_t acc[MI][4];
  #pragma unroll
  for (int i = 0; i < MI; i++)
    #pragma unroll
    for (int j = 0; j < 4; j++) acc[i][j] = (f32x4_t){0.f, 0.f, 0.f, 0.f};

  // prologue: halves 0,1,2 (= tile0 full + A0B0 of tile1); retire half 0
  stageA(0, 0); stageB(0, 0); stageA(0, 1); stageB(0, 1);
  stageA(1, 0); stageB(1, 0);
  WAITV(8);
  __builtin_amdgcn_s_barrier();

#define PHASE_MFMA(J0)                                                              \
  __builtin_amdgcn_s_setprio(1);                                                    \
  _Pragma("unroll")                                                                 \
  for (int i = 0; i < MI; i++) {                                                    \
    acc[i][J0]     = __builtin_amdgcn_mfma_f32_16x16x32_bf16(a0[i], b0[0], acc[i][J0], 0, 0, 0);     \
    acc[i][J0 + 1] = __builtin_amdgcn_mfma_f32_16x16x32_bf16(a0[i], b0[1], acc[i][J0 + 1], 0, 0, 0); \
  }                                                                                 \
  __builtin_amdgcn_s_setprio(0);

  for (int t = 0; t < NT; t++) {
    const u16* buf = lds + (t & 1) * BUF_E;
    const bool p1 = (t + 1 < NT);
    const bool p2 = (t + 2 < NT);
    bf16x8_t a0[MI], b0[2];

    // ---- phase 0: ks=0, n-frags 0,1 ; stage A1(t+1)  (half 2t+3, A-part)
    #pragma unroll
    for (int i = 0; i < MI; i++) a0[i] = readA(buf, 0, i);
    b0[0] = readB(buf, 0, 0); b0[1] = readB(buf, 0, 1);
    if (p1) stageA(t + 1, 1);
    __builtin_amdgcn_s_barrier();
    PHASE_MFMA(0)
    __builtin_amdgcn_s_barrier();

    // ---- phase 1: ks=0, n-frags 2,3 ; stage B1(t+1); retire half 2t+1 (ks1 of t)
    b0[0] = readB(buf, 0, 2); b0[1] = readB(buf, 0, 3);
    if (p1) stageB(t + 1, 1);
    if (p1) WAITV(8); else WAITV(0);
    __builtin_amdgcn_s_barrier();
    PHASE_MFMA(2)
    __builtin_amdgcn_s_barrier();

    // ---- phase 2: ks=1, n-frags 0,1 ; stage A0(t+2)  (half 2t+4, A-part)
    #pragma unroll
    for (int i = 0; i < MI; i++) a0[i] = readA(buf, 1, i);
    b0[0] = readB(buf, 1, 0); b0[1] = readB(buf, 1, 1);
    if (p2) stageA(t + 2, 0);
    __builtin_amdgcn_s_barrier();
    PHASE_MFMA(0)
    __builtin_amdgcn_s_barrier();

    // ---- phase 3: ks=1, n-frags 2,3 ; stage B0(t+2); retire half 2t+2 (ks0 of t+1)
    b0[0] = readB(buf, 1, 2); b0[1] = readB(buf, 1, 3);
    if (p2) stageB(t + 2, 0);
    if (p2) WAITV(8); else if (p1) WAITV(4);
    __builtin_amdgcn_s_barrier();
    PHASE_MFMA(2)
    __builtin_amdgcn_s_barrier();
  }
#undef PHASE_MFMA

  if constexpr (OUT_MODE == 2) {
    const int Nh = Nn >> 1;
    #pragma unroll
    for (int i = 0; i < MI; i++)
      #pragma unroll
      for (int jp = 0; jp < 2; jp++) {
        int c = (n0 + wc * 64 + jp * 32) / 2 + fr;
        #pragma unroll
        for (int r = 0; r < 4; r++) {
          int m = m0 + wr * (MI * 16) + i * 16 + fq * 4 + r;
          float g = acc[i][2 * jp][r], uu = acc[i][2 * jp + 1][r];
          ((u16*)Cv)[(size_t)m * Nh + c] = f2bf(gelu_fast(g) * uu);
        }
      }
  } else {
    #pragma unroll
    for (int i = 0; i < MI; i++)
      #pragma unroll
      for (int j = 0; j < 4; j++)
        #pragma unroll
        for (int r = 0; r < 4; r++) {
          int m = m0 + wr * (MI * 16) + i * 16 + fq * 4 + r;
          int n = n0 + wc * 64 + j * 16 + fr;
          ((u16*)Cv)[(size_t)m * Nn + n] = f2bf(acc[i][j][r]);
        }
  }
}

// ======== bf16 TN GEMM, MI=4 (BM=128): 3-slot LDS ring (R10-verified, unchanged) ========
// OUT_MODE: 0 = f32, 1 = bf16
template <int OUT_MODE>
__global__ __launch_bounds__(512, 2) void k_gemm4r(
    const u16* __restrict__ A, const u16* __restrict__ Bt, void* __restrict__ Cv,
    int Nn, int Kk) {
  constexpr int MI = 4;
  constexpr int BM = 128;
  constexpr int A_KS = BM * 32;            // 4096 elems
  constexpr int B_KS = 256 * 32;           // 8192 elems
  constexpr int SLOT_E = 2 * A_KS + 2 * B_KS;   // 24576 elems = 48 KB
  extern __shared__ u16 lds[];             // 3 * SLOT_E

  const int tid = threadIdx.x;
  const int wid = tid >> 6, lane = tid & 63;
  const int wr = wid >> 2, wc = wid & 3;
  const int fr = lane & 15, fq = lane >> 4;

  const int nwg = gridDim.x * gridDim.y;
  const int flat = blockIdx.y * gridDim.x + blockIdx.x;
  const int swz = (flat & 7) * (nwg >> 3) + (flat >> 3);
  const int m0 = (swz % gridDim.x) * BM;
  const int n0 = (swz / gridDim.x) * 256;
  const int NT = Kk >> 6;

  const int srow = lane >> 2, sslot = lane & 3;

  auto stageA = [&](int t, int ks) {
    u16* buf = lds + (t % 3) * SLOT_E + ks * A_KS;
    int row0 = wid * 16;
    int row = row0 + srow;
    int col = (sslot ^ ((row >> 1) & 3)) * 8;
    GLD_LDS16(A + (size_t)(m0 + row) * Kk + t * 64 + ks * 32 + col, buf + row0 * 32);
  };
  auto stageB = [&](int t, int ks) {
    u16* buf = lds + (t % 3) * SLOT_E + 2 * A_KS + ks * B_KS;
    #pragma unroll
    for (int i = 0; i < 2; i++) {
      int row0 = i * 128 + wid * 16;
      int row = row0 + srow;
      int col = (sslot ^ ((row >> 1) & 3)) * 8;
      GLD_LDS16(Bt + (size_t)(n0 + row) * Kk + t * 64 + ks * 32 + col, buf + row0 * 32);
    }
  };
  auto readA = [&](const u16* buf, int ks, int i) -> bf16x8_t {
    int row = wr * 64 + i * 16 + fr;
    return *(const bf16x8_t*)(buf + ks * A_KS + row * 32 + (fq ^ ((row >> 1) & 3)) * 8);
  };
  auto readB = [&](const u16* buf, int ks, int j) -> bf16x8_t {
    int row = wc * 64 + j * 16 + fr;
    return *(const bf16x8_t*)(buf + 2 * A_KS + ks * B_KS + row * 32 + (fq ^ ((row >> 1) & 3)) * 8);
  };

  f32x4_t acc[MI][4];
  #pragma unroll
  for (int i = 0; i < MI; i++)
    #pragma unroll
    for (int j = 0; j < 4; j++) acc[i][j] = (f32x4_t){0.f, 0.f, 0.f, 0.f};

  // prologue: stage tiles 0 and 1 fully (12 issues); retire A0B0(0)
  stageA(0, 0); stageB(0, 0); stageA(0, 1); stageB(0, 1);
  stageA(1, 0); stageB(1, 0); stageA(1, 1); stageB(1, 1);
  WAITV(9);
  __builtin_amdgcn_s_barrier();

#define PHASE_MFMA4(J0)                                                             \
  __builtin_amdgcn_s_setprio(1);                                                    \
  _Pragma("unroll")                                                                 \
  for (int i = 0; i < MI; i++) {                                                    \
    acc[i][J0]     = __builtin_amdgcn_mfma_f32_16x16x32_bf16(a0[i], b0[0], acc[i][J0], 0, 0, 0);     \
    acc[i][J0 + 1] = __builtin_amdgcn_mfma_f32_16x16x32_bf16(a0[i], b0[1], acc[i][J0 + 1], 0, 0, 0); \
  }                                                                                 \
  __builtin_amdgcn_s_setprio(0);

  for (int t = 0; t < NT; t++) {
    const u16* buf = lds + (t % 3) * SLOT_E;
    const bool pf2 = (t + 2 < NT);
    const bool pf1 = (t + 1 < NT);
    bf16x8_t a0[MI], b0[2];

    // ---- phase 0: ks=0, n-frags 0,1 ; stage A0(t+2)
    #pragma unroll
    for (int i = 0; i < MI; i++) a0[i] = readA(buf, 0, i);
    b0[0] = readB(buf, 0, 0); b0[1] = readB(buf, 0, 1);
    if (pf2) stageA(t + 2, 0);
    __builtin_amdgcn_s_barrier();
    PHASE_MFMA4(0)
    __builtin_amdgcn_s_barrier();

    // ---- phase 1: ks=0, n-frags 2,3 ; stage B0(t+2); retire A1B1(t)
    b0[0] = readB(buf, 0, 2); b0[1] = readB(buf, 0, 3);
    if (pf2) stageB(t + 2, 0);
    if (pf2) WAITV(9); else if (pf1) WAITV(6); else WAITV(0);
    __builtin_amdgcn_s_barrier();
    PHASE_MFMA4(2)
    __builtin_amdgcn_s_barrier();

    // ---- phase 2: ks=1, n-frags 0,1 ; stage A1(t+2)
    #pragma unroll
    for (int i = 0; i < MI; i++) a0[i] = readA(buf, 1, i);
    b0[0] = readB(buf, 1, 0); b0[1] = readB(buf, 1, 1);
    if (pf2) stageA(t + 2, 1);
    __builtin_amdgcn_s_barrier();
    PHASE_MFMA4(0)
    __builtin_amdgcn_s_barrier();

    // ---- phase 3: ks=1, n-frags 2,3 ; stage B1(t+2); retire A0B0(t+1)
    b0[0] = readB(buf, 1, 2); b0[1] = readB(buf, 1, 3);
    if (pf2) stageB(t + 2, 1);
    if (pf2) WAITV(9); else if (pf1) WAITV(3);
    __builtin_amdgcn_s_barrier();
    PHASE_MFMA4(2)
    __builtin_amdgcn_s_barrier();
  }
#undef PHASE_MFMA4

  #pragma unroll
  for (int i = 0; i < MI; i++)
    #pragma unroll
    for (int j = 0; j < 4; j++)
      #pragma unroll
      for (int r = 0; r < 4; r++) {
        int m = m0 + wr * 64 + i * 16 + fq * 4 + r;
        int n = n0 + wc * 64 + j * 16 + fr;
        float v = acc[i][j][r];
        if (OUT_MODE == 1) ((u16*)Cv)[(size_t)m * Nn + n] = f2bf(v);
        else ((float*)Cv)[(size_t)m * Nn + n] = v;
      }
}

// ===== fused QKV post: q/k RMSNorm+RoPE (table), v RMSNorm+transpose — one kernel =====
__global__ __launch_bounds__(64) void k_qkvpost(
    u16* __restrict__ qkv, const float* __restrict__ qscale,
    const float* __restrict__ kscale, const float2* __restrict__ rt,
    u16* __restrict__ vT) {
  int h = blockIdx.x % cNH, bt = blockIdx.x / cNH;
  int lane = threadIdx.x;
  u16* row = qkv + ((size_t)bt * cNH + h) * cH;
  float v[4], ssq = 0;
  #pragma unroll
  for (int m = 0; m < 4; m++) { v[m] = bf2f(row[lane + 64 * m]); ssq += v[m] * v[m]; }
  #pragma unroll
  for (int mm = 32; mm > 0; mm >>= 1) ssq += __shfl_xor(ssq, mm, 64);
  float rs = rsqrtf(ssq * (1.0f / cH) + cEPS);
  if (h < 10) {
    const float* sc = (h < 8) ? qscale : kscale;
    float os = (h < 8) ? cQS : 1.0f;
    #pragma unroll
    for (int m = 0; m < 4; m++) {
      int e = lane + 64 * m;
      v[m] = v[m] * rs * (1.0f + sc[e]);
    }
    #pragma unroll
    for (int m = 0; m < 2; m++) {
      int j = lane + 64 * m;
      float2 t = rt[bt * 128 + j];          // (sin, cos)
      float x1 = v[m], x2 = v[m + 2];
      row[j]       = f2bf((x1 * t.y - x2 * t.x) * os);
      row[j + 128] = f2bf((x2 * t.y + x1 * t.x) * os);
    }
  } else {
    int kk = h - 10;
    int b = bt / cT, t = bt % cT;
    #pragma unroll
    for (int m = 0; m < 4; m++) {
      int e = lane + 64 * m;
      vT[((size_t)(b * cK + kk) * cH + e) * cT + t] = f2bf(v[m] * rs);
    }
  }
}

// ===================== sliding-window GQA attention, 1 wave / 16-row Q tile =====================
__global__ __launch_bounds__(64) void k_attn(
    const u16* __restrict__ qkv, const u16* __restrict__ vT, u16* __restrict__ enc) {
  int t0 = blockIdx.x * 16;
  int n = blockIdx.y, b = blockIdx.z;
  int kn = n >> 2;                           // GQA group of 4
  int lane = threadIdx.x;
  int fr = lane & 15, fq = lane >> 4;
  __shared__ float P[16][33];                // +1 pad: kills 32-way conflict on transpose read

  bf16x8_t qf[8];
  const u16* qrow = qkv + ((size_t)(b * cT + t0 + fr) * cNH + n) * cH;
  #pragma unroll
  for (int ks = 0; ks < 8; ks++) qf[ks] = *(const bf16x8_t*)(qrow + ks * 32 + fq * 8);

  f32x4_t acc[16];
  #pragma unroll
  for (int ht = 0; ht < 16; ht++) acc[ht] = (f32x4_t){0.f, 0.f, 0.f, 0.f};
  float psum[4] = {0.f, 0.f, 0.f, 0.f};

  int s_lo = t0 - (cWIN - 1); if (s_lo < 0) s_lo = 0; s_lo &= ~31;
  for (int s0 = s_lo; s0 <= t0 + 15; s0 += 32) {
    f32x4_t S[2];
    S[0] = (f32x4_t){0.f, 0.f, 0.f, 0.f};
    S[1] = (f32x4_t){0.f, 0.f, 0.f, 0.f};
    #pragma unroll
    for (int c = 0; c < 2; c++) {
      const u16* krow = qkv + ((size_t)(b * cT + s0 + c * 16 + fr) * cNH + 8 + kn) * cH;
      #pragma unroll
      for (int ks = 0; ks < 8; ks++) {
        bf16x8_t kf = *(const bf16x8_t*)(krow + ks * 32 + fq * 8);
        S[c] = __builtin_amdgcn_mfma_f32_16x16x32_bf16(qf[ks], kf, S[c], 0, 0, 0);
      }
    }
    // soft-cap (fast tanh), mask, exp (fixed-max softmax: cap bounds logits to [-50,50])
    #pragma unroll
    for (int c = 0; c < 2; c++) {
      int s = s0 + c * 16 + fr;
      #pragma unroll
      for (int r = 0; r < 4; r++) {
        int t = t0 + fq * 4 + r;
        float l = cCAP * tanh_fast(S[c][r] * (1.0f / cCAP));
        float pe = (s <= t && s >= t - (cWIN - 1)) ? __expf(l) : 0.0f;
        psum[r] += pe;
        P[fq * 4 + r][c * 16 + fr] = pe;
      }
    }
    // transpose P via LDS into A-fragment layout (single wave: ds ops in order)
    bf16x8_t pf;
    #pragma unroll
    for (int e = 0; e < 8; e++) pf[e] = (short)f2bf(P[fr][fq * 8 + e]);
    #pragma unroll
    for (int ht = 0; ht < 16; ht++) {
      bf16x8_t vf = *(const bf16x8_t*)(vT + (((size_t)(b * cK + kn)) * cH + ht * 16 + fr) * cT + s0 + fq * 8);
      acc[ht] = __builtin_amdgcn_mfma_f32_16x16x32_bf16(pf, vf, acc[ht], 0, 0, 0);
    }
  }
  #pragma unroll
  for (int r = 0; r < 4; r++) {
    #pragma unroll
    for (int m = 1; m < 16; m <<= 1) psum[r] += __shfl_xor(psum[r], m, 64);
  }
  float inv[4];
  #pragma unroll
  for (int r = 0; r < 4; r++) inv[r] = 1.0f / psum[r];
  #pragma unroll
  for (int ht = 0; ht < 16; ht++)
    #pragma unroll
    for (int r = 0; r < 4; r++)
      enc[(((size_t)(b * cT + t0 + fq * 4 + r)) * cN + n) * cH + ht * 16 + fr] =
          f2bf(acc[ht][r] * inv[r]);
}

// ===================== post-attn: norm + residual + pre-FFW norm (float4) =====================
__global__ __launch_bounds__(256) void k_postattn(
    const float* __restrict__ attn_raw, const float* __restrict__ out0,
    const float* __restrict__ post_attn_scale, const float* __restrict__ pre_ffw_scale,
    float* __restrict__ ag, u16* __restrict__ h) {
  __shared__ float sbuf[4];
  int bt = blockIdx.x, tid = threadIdx.x;
  const size_t rowb = (size_t)bt * cD;
  float4 ar[2]; float ssq = 0;
  #pragma unroll
  for (int u = 0; u < 2; u++) {
    ar[u] = *(const float4*)(attn_raw + rowb + (u * 256 + tid) * 4);
    ssq += ar[u].x * ar[u].x + ar[u].y * ar[u].y + ar[u].z * ar[u].z + ar[u].w * ar[u].w;
  }
  float rs = rsqrtf(block_sum256(ssq, sbuf) * (1.0f / cD) + cEPS);
  float4 agv[2]; float ssq2 = 0;
  #pragma unroll
  for (int u = 0; u < 2; u++) {
    int e0 = (u * 256 + tid) * 4;
    float4 o0 = *(const float4*)(out0 + rowb + e0);
    float4 sc = *(const float4*)(post_attn_scale + e0);
    float4 a;
    a.x = o0.x + ar[u].x * rs * (1.0f + sc.x);
    a.y = o0.y + ar[u].y * rs * (1.0f + sc.y);
    a.z = o0.z + ar[u].z * rs * (1.0f + sc.z);
    a.w = o0.w + ar[u].w * rs * (1.0f + sc.w);
    agv[u] = a;
    *(float4*)(ag + rowb + e0) = a;
    ssq2 += a.x * a.x + a.y * a.y + a.z * a.z + a.w * a.w;
  }
  float rs2 = rsqrtf(block_sum256(ssq2, sbuf) * (1.0f / cD) + cEPS);
  #pragma unroll
  for (int u = 0; u < 2; u++) {
    int e0 = (u * 256 + tid) * 4;
    float4 sc = *(const float4*)(pre_ffw_scale + e0);
    store_bf4(h + rowb + e0,
              agv[u].x * rs2 * (1.0f + sc.x), agv[u].y * rs2 * (1.0f + sc.y),
              agv[u].z * rs2 * (1.0f + sc.z), agv[u].w * rs2 * (1.0f + sc.w));
  }
}

// ======= post-FFW norm + residual + AltUp correct, in-place on out (float4) =======
__global__ __launch_bounds__(256) void k_final(
    const float* __restrict__ ffw_raw, const float* __restrict__ ag,
    const float* __restrict__ post_ffw_scale, const float* __restrict__ cos_scale,
    const float* __restrict__ router_w, const float* __restrict__ corr_coefs,
    float* __restrict__ out) {
  __shared__ float sbuf[16];
  int bt = blockIdx.x, tid = threadIdx.x;
  const size_t PL = (size_t)cBT * cD;
  const size_t rowb = (size_t)bt * cD;
  float4 fv[2]; float ssq = 0;
  #pragma unroll
  for (int u = 0; u < 2; u++) {
    fv[u] = *(const float4*)(ffw_raw + rowb + (u * 256 + tid) * 4);
    ssq += fv[u].x * fv[u].x + fv[u].y * fv[u].y + fv[u].z * fv[u].z + fv[u].w * fv[u].w;
  }
  float rs = rsqrtf(block_sum256(ssq, sbuf) * (1.0f / cD) + cEPS);
  float4 av[2];
  float rp[4] = {0, 0, 0, 0};
  #pragma unroll
  for (int u = 0; u < 2; u++) {
    int e0 = (u * 256 + tid) * 4;
    float4 agx = *(const float4*)(ag + rowb + e0);
    float4 ps = *(const float4*)(post_ffw_scale + e0);
    float4 cs = *(const float4*)(cos_scale + e0);
    float4 a;
    a.x = (agx.x + fv[u].x * rs * (1.0f + ps.x)) * cs.x;
    a.y = (agx.y + fv[u].y * rs * (1.0f + ps.y)) * cs.y;
    a.z = (agx.z + fv[u].z * rs * (1.0f + ps.z)) * cs.z;
    a.w = (agx.w + fv[u].w * rs * (1.0f + ps.w)) * cs.w;
    av[u] = a;
    #pragma unroll
    for (int k = 0; k < 4; k++) {
      float4 rw = *(const float4*)(router_w + (size_t)(e0 + k) * 4);
      float xe = g4(a, k);
      rp[0] += xe * rw.x; rp[1] += xe * rw.y; rp[2] += xe * rw.z; rp[3] += xe * rw.w;
    }
  }
  block_sum256x4(rp, sbuf);
  float cc[4];
  #pragma unroll
  for (int i = 0; i < 4; i++) {
    float s = 1.0f;
    #pragma unroll
    for (int p = 0; p < 4; p++) s += tanh_fast(rp[p] * (1.0f / cD)) * corr_coefs[p * 4 + i];
    cc[i] = s;
  }
  #pragma unroll
  for (int u = 0; u < 2; u++) {
    size_t o = rowb + (u * 256 + tid) * 4;
    float4 p0 = *(const float4*)(out + o);
    float4 in4;
    in4.x = av[u].x - p0.x; in4.y = av[u].y - p0.y;
    in4.z = av[u].z - p0.z; in4.w = av[u].w - p0.w;
    float4 w0;
    w0.x = p0.x + cc[0] * in4.x; w0.y = p0.y + cc[0] * in4.y;
    w0.z = p0.z + cc[0] * in4.z; w0.w = p0.w + cc[0] * in4.w;
    *(float4*)(out + o) = w0;
    #pragma unroll
    for (int i = 1; i < 4; i++) {
      float4 q = *(const float4*)(out + i * PL + o);
      q.x += cc[i] * in4.x; q.y += cc[i] * in4.y;
      q.z += cc[i] * in4.z; q.w += cc[i] * in4.w;
      *(float4*)(out + i * PL + o) = q;
    }
  }
}

// =============================================================================
extern "C" void kernel_launch(void* const* d_in, const int* in_sizes, int n_in,
                              void* d_out, int out_size, void* d_ws, size_t ws_size,
                              hipStream_t stream) {
  const float* x              = (const float*)d_in[0];
  const int*   pos            = (const int*)d_in[1];
  // d_in[2] attn_mask: equals causal(pos) — recomputed from positions in-kernel
  const float* router_w       = (const float*)d_in[3];
  const float* pred_coefs     = (const float*)d_in[4];
  const float* corr_coefs     = (const float*)d_in[5];
  const float* cos_scale      = (const float*)d_in[6];
  const float* pre_attn_scale = (const float*)d_in[7];
  const float* q_w            = (const float*)d_in[8];
  const float* kv_w           = (const float*)d_in[9];
  const float* qk_q_scale     = (const float*)d_in[10];
  const float* qk_k_scale     = (const float*)d_in[11];
  const float* o_w            = (const float*)d_in[12];
  const float* post_attn_scale= (const float*)d_in[13];
  const float* pre_ffw_scale  = (const float*)d_in[14];
  const float* gate_w         = (const float*)d_in[15];
  const float* up_w           = (const float*)d_in[16];
  const float* down_w         = (const float*)d_in[17];
  const float* post_ffw_scale = (const float*)d_in[18];
  float* out = (float*)d_out;

  char* wsp = (char*)d_ws;
  size_t off = 0;
  auto take = [&](size_t nbytes) -> char* {
    char* p = wsp + off;
    off += (nbytes + 255) & ~((size_t)255);
    return p;
  };
  u16* gu_wT    = (u16*)take((size_t)2 * cF * cD * 2);          // [16384][2048], 16-col interleave
  u16* down_wT  = (u16*)take((size_t)cD * cF * 2);              // [2048][8192]
  u16* qkv_wT   = (u16*)take((size_t)cNH * cH * cD * 2);        // [3072][2048]
  u16* o_wT     = (u16*)take((size_t)cD * cN * cH * 2);         // [2048][2048]
  u16* attn_in  = (u16*)take((size_t)cBT * cD * 2);
  u16* qkvbuf   = (u16*)take((size_t)cBT * cNH * cH * 2);       // [BT][3072]
  u16* vTbuf    = (u16*)take((size_t)cB * cK * cH * cT * 2);
  u16* encbuf   = (u16*)take((size_t)cBT * cN * cH * 2);
  float* attn_raw = (float*)take((size_t)cBT * cD * 4);
  float* agbuf    = (float*)take((size_t)cBT * cD * 4);
  u16* hbuf     = (u16*)take((size_t)cBT * cD * 2);
  u16* Gcbuf    = (u16*)take((size_t)cBT * cF * 2);             // gelu(G)*U, [BT][8192]
  float* ffw_raw = (float*)take((size_t)cBT * cD * 4);
  float2* ropetab = (float2*)take((size_t)cBT * 128 * 8);
  (void)in_sizes; (void)n_in; (void)out_size; (void)ws_size;

  dim3 blk256(256), blk64(64), blk512(512);
  constexpr unsigned LDS8  = 2 * (2 * 256 * 32 + 2 * 256 * 32) * 2;   // 128 KiB
  constexpr unsigned LDS4R = 3 * (2 * 128 * 32 + 2 * 256 * 32) * 2;   // 144 KiB

  // ---- weight prep: transpose + cast to bf16 (TN layout); gate/up 16-col interleaved ----
  k_transpose_cast<<<dim3(cF / 64, cD / 64, 1), blk256, 0, stream>>>(gate_w, gu_wT, cD, cF, 0);
  k_transpose_cast<<<dim3(cF / 64, cD / 64, 1), blk256, 0, stream>>>(up_w, gu_wT, cD, cF, 1);
  k_transpose_cast<<<dim3(cD / 64, cF / 64, 1), blk256, 0, stream>>>(down_w, down_wT, cF, cD, -1);
  k_transpose_cast<<<dim3(cH / 64, cD / 64, cN), blk256, 0, stream>>>(q_w, qkv_wT, cD, cH, -1);
  k_transpose_cast<<<dim3(cH / 64, cD / 64, 2 * cK), blk256, 0, stream>>>(
      kv_w, qkv_wT + (size_t)cN * cH * cD, cD, cH, -1);
  k_transpose_cast<<<dim3(cD / 64, (cN * cH) / 64, 1), blk256, 0, stream>>>(o_w, o_wT, cN * cH, cD, -1);
  k_rope_table<<<dim3(cBT * 128 / 256), blk256, 0, stream>>>(pos, ropetab);

  // ---- AltUp predict (writes predictions into d_out) + pre-attn RMSNorm ----
  k_predict<<<dim3(cBT), blk256, 0, stream>>>(x, router_w, pred_coefs, pre_attn_scale, out, attn_in);

  // ---- fused QKV projection: [4096,2048] x [3072,2048]^T ----
  k_gemm4r<1><<<dim3(cBT / 128, (cNH * cH) / 256), blk512, LDS4R, stream>>>(
      attn_in, qkv_wT, qkvbuf, cNH * cH, cD);

  // ---- fused QK-norm+RoPE / V-norm+transpose ----
  k_qkvpost<<<dim3(cBT * cNH), blk64, 0, stream>>>(qkvbuf, qk_q_scale, qk_k_scale, ropetab, vTbuf);

  // ---- sliding-window attention ----
  k_attn<<<dim3(cT / 16, cN, cB), blk64, 0, stream>>>(qkvbuf, vTbuf, encbuf);

  // ---- O projection + post-attn norm/residual + pre-FFW norm ----
  k_gemm4r<0><<<dim3(cBT / 128, cD / 256), blk512, LDS4R, stream>>>(
      encbuf, o_wT, attn_raw, cD, cN * cH);
  k_postattn<<<dim3(cBT), blk256, 0, stream>>>(attn_raw, out, post_attn_scale, pre_ffw_scale, agbuf, hbuf);

  // ---- FFN: fused gate+up GEMM (MI=8, deepened staging) with gelu-mul epilogue, then down GEMM ----
  k_gemm8w<2><<<dim3(cBT / 256, (2 * cF) / 256), blk512, LDS8, stream>>>(
      hbuf, gu_wT, Gcbuf, 2 * cF, cD);
  k_gemm4r<0><<<dim3(cBT / 128, cD / 256), blk512, LDS4R, stream>>>(
      Gcbuf, down_wT, ffw_raw, cD, cF);

  // ---- post-FFW norm/residual + AltUp correct ----
  k_final<<<dim3(cBT), blk256, 0, stream>>>(ffw_raw, agbuf, post_ffw_scale, cos_scale,
                                            router_w, corr_coefs, out);
}